// Round 1
// baseline (4666.895 us; speedup 1.0000x reference)
//
#include <hip/hip_runtime.h>
#include <hip/hip_bf16.h>
#include <math.h>

// Problem constants
#define NB    64            // batch
#define LSEQ  196           // H*W = 14*14
#define HID   768
#define NHEAD 24
#define HDIM  32
#define FFN   3072
#define ROWS  (NB * LSEQ)   // 12544
#define RATE  0.2f
#define LN_EPS 1e-5f

// ---------------------------------------------------------------------------
// LayerNorm over last dim (768). One block (256 threads) per row.
// ---------------------------------------------------------------------------
__global__ __launch_bounds__(256) void ln_kernel(
    const float* __restrict__ x, const float* __restrict__ g,
    const float* __restrict__ b, float* __restrict__ y)
{
    int row = blockIdx.x;
    int tid = threadIdx.x;  // 0..255
    const float* xr = x + (size_t)row * HID;
    float v0 = xr[tid], v1 = xr[tid + 256], v2 = xr[tid + 512];
    __shared__ float rs[256], rs2[256];
    rs[tid]  = v0 + v1 + v2;
    rs2[tid] = v0 * v0 + v1 * v1 + v2 * v2;
    __syncthreads();
    for (int off = 128; off > 0; off >>= 1) {
        if (tid < off) { rs[tid] += rs[tid + off]; rs2[tid] += rs2[tid + off]; }
        __syncthreads();
    }
    float mean = rs[0] * (1.0f / HID);
    float var  = rs2[0] * (1.0f / HID) - mean * mean;
    float rstd = rsqrtf(var + LN_EPS);
    float* yr = y + (size_t)row * HID;
    yr[tid]       = (v0 - mean) * rstd * g[tid]       + b[tid];
    yr[tid + 256] = (v1 - mean) * rstd * g[tid + 256] + b[tid + 256];
    yr[tid + 512] = (v2 - mean) * rstd * g[tid + 512] + b[tid + 512];
}

// ---------------------------------------------------------------------------
// Per-head QKV projection: q[.,e] = sum_d x[.,d] * wq[e][d] (heads share W).
// One block (768 threads) per token row; W cached in LDS with +1 pad
// (stride 33) to avoid the 32-way bank conflict of stride-32 reads.
// ---------------------------------------------------------------------------
__global__ __launch_bounds__(768) void qkv_kernel(
    const float* __restrict__ y,
    const float* __restrict__ wq, const float* __restrict__ wk,
    const float* __restrict__ wv,
    float* __restrict__ q, float* __restrict__ k, float* __restrict__ v)
{
    int row = blockIdx.x;   // 0..12543
    int tid = threadIdx.x;  // 0..767
    __shared__ float xs[HID];
    __shared__ float wqs[32 * 33], wks[32 * 33], wvs[32 * 33];
    xs[tid] = y[(size_t)row * HID + tid];
    for (int i = tid; i < 1024; i += 768) {
        int e = i >> 5, d = i & 31;
        wqs[e * 33 + d] = wq[i];
        wks[e * 33 + d] = wk[i];
        wvs[e * 33 + d] = wv[i];
    }
    __syncthreads();
    int h = tid >> 5, e = tid & 31;
    const float* xv = xs + h * 32;
    float aq = 0.f, ak = 0.f, av = 0.f;
#pragma unroll
    for (int d = 0; d < 32; d++) {
        float xd = xv[d];
        aq += xd * wqs[e * 33 + d];
        ak += xd * wks[e * 33 + d];
        av += xd * wvs[e * 33 + d];
    }
    size_t o = (size_t)row * HID + tid;
    q[o] = aq; k[o] = ak; v[o] = av;
}

// ---------------------------------------------------------------------------
// Attention: one block (256 threads) per (n, h, q-row).
// scores(196) + rel_bias -> softmax -> o(32) = a @ v.
// ---------------------------------------------------------------------------
__global__ __launch_bounds__(256) void attn_kernel(
    const float* __restrict__ q, const float* __restrict__ k,
    const float* __restrict__ v, const float* __restrict__ rel_bias,
    float* __restrict__ o)
{
    int qi = blockIdx.x;  // 0..195
    int h  = blockIdx.y;  // 0..23
    int n  = blockIdx.z;  // 0..63
    int tid = threadIdx.x;

    __shared__ float qs[32];
    __shared__ float sc[LSEQ];
    __shared__ float red[256];

    size_t base = (size_t)n * LSEQ * HID + (size_t)h * HDIM;
    if (tid < 32) qs[tid] = q[base + (size_t)qi * HID + tid];
    __syncthreads();

    const float inv_sqrt_d = 0.17677669529663687f;  // 1/sqrt(32)
    if (tid < LSEQ) {
        const float* kr = k + base + (size_t)tid * HID;
        float s = 0.f;
#pragma unroll
        for (int d = 0; d < 32; d++) s += qs[d] * kr[d];
        int i  = qi / 14, j  = qi - i * 14;
        int ip = tid / 14, jp = tid - ip * 14;
        float bias = rel_bias[(i - ip + 14) * 28 + (j - jp + 14)];
        sc[tid] = (s + bias) * inv_sqrt_d;
    }
    __syncthreads();

    // max reduction
    red[tid] = (tid < LSEQ) ? sc[tid] : -1e30f;
    __syncthreads();
    for (int off = 128; off > 0; off >>= 1) {
        if (tid < off) red[tid] = fmaxf(red[tid], red[tid + off]);
        __syncthreads();
    }
    float mx = red[0];
    __syncthreads();

    float ev = (tid < LSEQ) ? __expf(sc[tid] - mx) : 0.f;
    if (tid < LSEQ) sc[tid] = ev;
    red[tid] = ev;
    __syncthreads();
    for (int off = 128; off > 0; off >>= 1) {
        if (tid < off) red[tid] += red[tid + off];
        __syncthreads();
    }
    float rdenom = 1.0f / red[0];
    __syncthreads();

    // o[e] = (1/denom) * sum_k sc[k] * v[n,k,h,e]; 8 k-groups x 32 e-lanes
    int g = tid >> 5;   // 0..7
    int e = tid & 31;   // 0..31
    float acc = 0.f;
    for (int kk = g; kk < LSEQ; kk += 8)
        acc += sc[kk] * v[base + (size_t)kk * HID + e];
    red[tid] = acc;
    __syncthreads();
    if (g == 0) {
        float s2 = 0.f;
#pragma unroll
        for (int gg = 0; gg < 8; gg++) s2 += red[gg * 32 + e];
        o[base + (size_t)qi * HID + e] = s2 * rdenom;
    }
}

// ---------------------------------------------------------------------------
// Tiled fp32 GEMM:  C[m,n] = sum_k A[m,k] * B[n,k]   (B stored N x K, torch
// Linear weight layout). 64x64 tile, BK=16, 256 threads, 4x4 per thread.
// Epilogue modes: 0: C=acc
//                 1: C=(res+acc)*scale
//                 2: C=gelu(acc+bias)          (exact erf gelu)
//                 3: C=(res+acc+bias)*scale
// M,N,K all multiples of tile sizes for this problem (no bound guards).
// ---------------------------------------------------------------------------
__device__ __forceinline__ float gelu_exact(float x) {
    return 0.5f * x * (1.0f + erff(x * 0.70710678118654752f));
}

__global__ __launch_bounds__(256) void gemm_bt_kernel(
    const float* __restrict__ A, const float* __restrict__ B,
    float* __restrict__ C, int M, int N, int K,
    int mode, const float* __restrict__ bias,
    const float* __restrict__ res, float scale)
{
    __shared__ float As[16][65];
    __shared__ float Bs[16][65];
    int bm = blockIdx.y * 64;
    int bn = blockIdx.x * 64;
    int tid = threadIdx.x;          // 0..255
    int tx = tid & 15, ty = tid >> 4;
    float acc[4][4] = {};

    for (int k0 = 0; k0 < K; k0 += 16) {
#pragma unroll
        for (int i = 0; i < 4; i++) {
            int idx = tid + i * 256;        // 0..1023
            int r = idx >> 4;               // 0..63
            int kk = idx & 15;              // 0..15
            As[kk][r] = A[(size_t)(bm + r) * K + k0 + kk];
            Bs[kk][r] = B[(size_t)(bn + r) * K + k0 + kk];
        }
        __syncthreads();
#pragma unroll
        for (int kk = 0; kk < 16; kk++) {
            float a[4], b[4];
#pragma unroll
            for (int i = 0; i < 4; i++) { a[i] = As[kk][ty * 4 + i]; b[i] = Bs[kk][tx * 4 + i]; }
#pragma unroll
            for (int i = 0; i < 4; i++)
#pragma unroll
                for (int j = 0; j < 4; j++) acc[i][j] += a[i] * b[j];
        }
        __syncthreads();
    }

#pragma unroll
    for (int i = 0; i < 4; i++) {
        int m = bm + ty * 4 + i;
#pragma unroll
        for (int j = 0; j < 4; j++) {
            int n = bn + tx * 4 + j;
            float vacc = acc[i][j];
            if (mode == 1) {
                vacc = (res[(size_t)m * N + n] + vacc) * scale;
            } else if (mode == 2) {
                vacc = gelu_exact(vacc + bias[n]);
            } else if (mode == 3) {
                vacc = (res[(size_t)m * N + n] + vacc + bias[n]) * scale;
            }
            C[(size_t)m * N + n] = vacc;
        }
    }
}

// ---------------------------------------------------------------------------
// Launch
// ---------------------------------------------------------------------------
extern "C" void kernel_launch(void* const* d_in, const int* in_sizes, int n_in,
                              void* d_out, int out_size, void* d_ws, size_t ws_size,
                              hipStream_t stream)
{
    const float* x        = (const float*)d_in[0];
    const float* rel_bias = (const float*)d_in[1];
    const float* wq       = (const float*)d_in[2];
    const float* wk       = (const float*)d_in[3];
    const float* wv       = (const float*)d_in[4];
    const float* w_out    = (const float*)d_in[5];
    const float* ln1_g    = (const float*)d_in[6];
    const float* ln1_b    = (const float*)d_in[7];
    const float* ln2_g    = (const float*)d_in[8];
    const float* ln2_b    = (const float*)d_in[9];
    const float* w1       = (const float*)d_in[10];
    const float* b1       = (const float*)d_in[11];
    const float* w2       = (const float*)d_in[12];
    const float* b2       = (const float*)d_in[13];
    float* out = (float*)d_out;
    float* ws  = (float*)d_ws;

    const size_t SZ = (size_t)ROWS * HID;  // 9,633,792 floats
    float* y1 = ws;              // [0, SZ)        LN1 output; later o reuses it
    float* q  = ws + SZ;         // [SZ, 2SZ)
    float* k  = ws + 2 * SZ;     // [2SZ, 3SZ)
    float* v  = ws + 3 * SZ;     // [3SZ, 4SZ)
    float* o  = ws;              // reuse y1 region (dead after qkv)
    float* h  = ws;              // FFN hidden, [0, 4SZ) — y1/q/k/v dead by then
    float* y2 = ws + 4 * SZ;     // [4SZ, 5SZ)
    // x1 (post-attention residual) lives in d_out.

    // 1. y1 = LN1(x)
    ln_kernel<<<ROWS, 256, 0, stream>>>(x, ln1_g, ln1_b, y1);

    // 2. q,k,v per-head projections
    qkv_kernel<<<ROWS, 768, 0, stream>>>(y1, wq, wk, wv, q, k, v);

    // 3. o = softmax((qk^T + bias)/sqrt(d)) @ v
    attn_kernel<<<dim3(LSEQ, NHEAD, NB), 256, 0, stream>>>(q, k, v, rel_bias, o);

    // 4. x1 = (x + o @ w_out^T) * RATE   -> d_out
    gemm_bt_kernel<<<dim3(HID / 64, ROWS / 64), 256, 0, stream>>>(
        o, w_out, out, ROWS, HID, HID, /*mode=*/1, nullptr, x, RATE);

    // 5. y2 = LN2(x1)
    ln_kernel<<<ROWS, 256, 0, stream>>>(out, ln2_g, ln2_b, y2);

    // 6. h = gelu(y2 @ w1^T + b1)
    gemm_bt_kernel<<<dim3(FFN / 64, ROWS / 64), 256, 0, stream>>>(
        y2, w1, h, ROWS, FFN, HID, /*mode=*/2, b1, nullptr, 1.0f);

    // 7. out = (x1 + h @ w2^T + b2) * RATE   (reads+writes d_out elementwise)
    gemm_bt_kernel<<<dim3(HID / 64, ROWS / 64), 256, 0, stream>>>(
        h, w2, out, ROWS, HID, FFN, /*mode=*/3, b2, out, RATE);
}

// Round 2
// 1152.735 us; speedup vs baseline: 4.0485x; 4.0485x over previous
//
#include <hip/hip_runtime.h>
#include <hip/hip_bf16.h>
#include <math.h>

// Problem constants
#define NB    64            // batch
#define LSEQ  196           // H*W = 14*14
#define HID   768
#define NHEAD 24
#define HDIM  32
#define FFN   3072
#define ROWS  (NB * LSEQ)   // 12544
#define RATE  0.2f
#define LN_EPS 1e-5f

typedef short s16x8 __attribute__((ext_vector_type(8)));   // 8 bf16 (4 VGPRs)
typedef float f32x4 __attribute__((ext_vector_type(4)));   // MFMA accumulator

// fp32 -> bf16 round-to-nearest-even (bit pattern in ushort)
__device__ __forceinline__ unsigned short f2bf(float f) {
    unsigned u = __float_as_uint(f);
    unsigned r = u + 0x7fffu + ((u >> 16) & 1u);
    return (unsigned short)(r >> 16);
}

// ---------------------------------------------------------------------------
// LayerNorm over last dim (768). One block (256 threads) per row.
// ---------------------------------------------------------------------------
__global__ __launch_bounds__(256) void ln_kernel(
    const float* __restrict__ x, const float* __restrict__ g,
    const float* __restrict__ b, float* __restrict__ y)
{
    int row = blockIdx.x;
    int tid = threadIdx.x;  // 0..255
    const float* xr = x + (size_t)row * HID;
    float v0 = xr[tid], v1 = xr[tid + 256], v2 = xr[tid + 512];
    __shared__ float rs[256], rs2[256];
    rs[tid]  = v0 + v1 + v2;
    rs2[tid] = v0 * v0 + v1 * v1 + v2 * v2;
    __syncthreads();
    for (int off = 128; off > 0; off >>= 1) {
        if (tid < off) { rs[tid] += rs[tid + off]; rs2[tid] += rs2[tid + off]; }
        __syncthreads();
    }
    float mean = rs[0] * (1.0f / HID);
    float var  = rs2[0] * (1.0f / HID) - mean * mean;
    float rstd = rsqrtf(var + LN_EPS);
    float* yr = y + (size_t)row * HID;
    yr[tid]       = (v0 - mean) * rstd * g[tid]       + b[tid];
    yr[tid + 256] = (v1 - mean) * rstd * g[tid + 256] + b[tid + 256];
    yr[tid + 512] = (v2 - mean) * rstd * g[tid + 512] + b[tid + 512];
}

// ---------------------------------------------------------------------------
// Per-head QKV projection (heads share 32x32 weights). One block per row.
// ---------------------------------------------------------------------------
__global__ __launch_bounds__(768) void qkv_kernel(
    const float* __restrict__ y,
    const float* __restrict__ wq, const float* __restrict__ wk,
    const float* __restrict__ wv,
    float* __restrict__ q, float* __restrict__ k, float* __restrict__ v)
{
    int row = blockIdx.x;   // 0..12543
    int tid = threadIdx.x;  // 0..767
    __shared__ float xs[HID];
    __shared__ float wqs[32 * 33], wks[32 * 33], wvs[32 * 33];
    xs[tid] = y[(size_t)row * HID + tid];
    for (int i = tid; i < 1024; i += 768) {
        int e = i >> 5, d = i & 31;
        wqs[e * 33 + d] = wq[i];
        wks[e * 33 + d] = wk[i];
        wvs[e * 33 + d] = wv[i];
    }
    __syncthreads();
    int h = tid >> 5, e = tid & 31;
    const float* xv = xs + h * 32;
    float aq = 0.f, ak = 0.f, av = 0.f;
#pragma unroll
    for (int d = 0; d < 32; d++) {
        float xd = xv[d];
        aq += xd * wqs[e * 33 + d];
        ak += xd * wks[e * 33 + d];
        av += xd * wvs[e * 33 + d];
    }
    size_t o = (size_t)row * HID + tid;
    q[o] = aq; k[o] = ak; v[o] = av;
}

// ---------------------------------------------------------------------------
// Attention v2: one block (256 threads) per (h, n). K,V,bias staged in LDS
// once; thread t owns q-row t (t<196) and runs online softmax over all 196
// keys with Q and the 32-float O accumulator in registers. All lanes walk k
// in lockstep -> every LDS read is a same-address broadcast (conflict-free).
// ---------------------------------------------------------------------------
__global__ __launch_bounds__(256) void attn_kernel(
    const float* __restrict__ q, const float* __restrict__ k,
    const float* __restrict__ v, const float* __restrict__ rel_bias,
    float* __restrict__ o)
{
    int h = blockIdx.x;   // 0..23
    int n = blockIdx.y;   // 0..63
    int tid = threadIdx.x;

    __shared__ float Ks[LSEQ * 32];  // 25088 B
    __shared__ float Vs[LSEQ * 32];  // 25088 B
    __shared__ float bs[28 * 28];    //  3136 B

    size_t base = (size_t)n * LSEQ * HID + (size_t)h * HDIM;

    // stage K, V: 196*32/4 = 1568 float4 each
    for (int i = tid; i < 1568; i += 256) {
        int r = i >> 3, c4 = i & 7;
        *(float4*)&Ks[r * 32 + c4 * 4] = *(const float4*)&k[base + (size_t)r * HID + c4 * 4];
        *(float4*)&Vs[r * 32 + c4 * 4] = *(const float4*)&v[base + (size_t)r * HID + c4 * 4];
    }
    for (int i = tid; i < 784; i += 256) bs[i] = rel_bias[i];
    __syncthreads();

    if (tid < LSEQ) {
        // Q row into registers
        float4 q4[8];
        const float4* qg = (const float4*)&q[base + (size_t)tid * HID];
#pragma unroll
        for (int i = 0; i < 8; i++) q4[i] = qg[i];

        int qi_i = tid / 14, qi_j = tid - qi_i * 14;
        int bbase = (qi_i + 14) * 28 + (qi_j + 14);
        const float inv_sqrt_d = 0.17677669529663687f;  // 1/sqrt(32)

        float m = -INFINITY, l = 0.f;
        float4 o4[8] = {};

        for (int ip = 0; ip < 14; ip++) {
            int brow = bbase - ip * 28;
            for (int jp = 0; jp < 14; jp++) {
                int kk = ip * 14 + jp;
                const float4* kr = (const float4*)&Ks[kk * 32];
                float s = 0.f;
#pragma unroll
                for (int i = 0; i < 8; i++) {
                    s += q4[i].x * kr[i].x + q4[i].y * kr[i].y
                       + q4[i].z * kr[i].z + q4[i].w * kr[i].w;
                }
                s = (s + bs[brow - jp]) * inv_sqrt_d;
                if (s > m) {
                    float alpha = __expf(m - s);
                    l *= alpha;
#pragma unroll
                    for (int i = 0; i < 8; i++) {
                        o4[i].x *= alpha; o4[i].y *= alpha;
                        o4[i].z *= alpha; o4[i].w *= alpha;
                    }
                    m = s;
                }
                float p = __expf(s - m);
                l += p;
                const float4* vr = (const float4*)&Vs[kk * 32];
#pragma unroll
                for (int i = 0; i < 8; i++) {
                    o4[i].x += p * vr[i].x; o4[i].y += p * vr[i].y;
                    o4[i].z += p * vr[i].z; o4[i].w += p * vr[i].w;
                }
            }
        }
        float inv_l = 1.0f / l;
        float4* og = (float4*)&o[base + (size_t)tid * HID];
#pragma unroll
        for (int i = 0; i < 8; i++) {
            float4 t = o4[i];
            t.x *= inv_l; t.y *= inv_l; t.z *= inv_l; t.w *= inv_l;
            og[i] = t;
        }
    }
}

// ---------------------------------------------------------------------------
// bf16 MFMA GEMM: C[m,n] = sum_k A[m,k]*B[n,k] (B is torch Linear weight,
// N x K). 64x64 tile, BK=32, 256 threads = 4 waves, each wave a 32x32
// quadrant = 2x2 MFMA tiles of 16x16x32. A/B converted fp32->bf16 while
// staging to LDS (row stride 40 bf16: 16B-aligned b128 reads, 2-way bank
// aliasing = free). Epilogue modes as before:
//   0: C=acc   1: C=(res+acc)*scale   2: C=gelu(acc+bias)
//   3: C=(res+acc+bias)*scale
// ---------------------------------------------------------------------------
__device__ __forceinline__ float gelu_exact(float x) {
    return 0.5f * x * (1.0f + erff(x * 0.70710678118654752f));
}

__global__ __launch_bounds__(256) void gemm_mfma_kernel(
    const float* __restrict__ A, const float* __restrict__ B,
    float* __restrict__ C, int M, int N, int K,
    int mode, const float* __restrict__ bias,
    const float* __restrict__ res, float scale)
{
    __shared__ __align__(16) unsigned short As[64 * 40];  // 5120 B
    __shared__ __align__(16) unsigned short Bs[64 * 40];  // 5120 B

    int tid = threadIdx.x;            // 0..255
    int bm = blockIdx.y * 64;
    int bn = blockIdx.x * 64;
    int w    = tid >> 6;              // wave 0..3
    int lane = tid & 63;
    int wm = (w & 1) * 32;
    int wn = (w >> 1) * 32;
    int lr = lane & 15;               // frag row (m for A, n for B, col for C/D)
    int lq = lane >> 4;               // quad (k-group for A/B, row-group for C/D)

    f32x4 acc[2][2] = {};

    for (int k0 = 0; k0 < K; k0 += 32) {
        // stage A,B tiles (64x32 fp32 -> bf16). 512 packed-4 groups, 2/thread.
#pragma unroll
        for (int i = 0; i < 2; i++) {
            int idx = tid + i * 256;      // 0..511
            int r = idx >> 3, c4 = idx & 7;
            float4 av = *(const float4*)&A[(size_t)(bm + r) * K + k0 + c4 * 4];
            float4 bv = *(const float4*)&B[(size_t)(bn + r) * K + k0 + c4 * 4];
            uint2 pa, pb;
            pa.x = (unsigned)f2bf(av.x) | ((unsigned)f2bf(av.y) << 16);
            pa.y = (unsigned)f2bf(av.z) | ((unsigned)f2bf(av.w) << 16);
            pb.x = (unsigned)f2bf(bv.x) | ((unsigned)f2bf(bv.y) << 16);
            pb.y = (unsigned)f2bf(bv.z) | ((unsigned)f2bf(bv.w) << 16);
            *(uint2*)&As[r * 40 + c4 * 4] = pa;
            *(uint2*)&Bs[r * 40 + c4 * 4] = pb;
        }
        __syncthreads();

        s16x8 af[2], bf[2];
#pragma unroll
        for (int t = 0; t < 2; t++) {
            af[t] = *(const s16x8*)&As[(wm + t * 16 + lr) * 40 + lq * 8];
            bf[t] = *(const s16x8*)&Bs[(wn + t * 16 + lr) * 40 + lq * 8];
        }
#pragma unroll
        for (int tm = 0; tm < 2; tm++)
#pragma unroll
            for (int tn = 0; tn < 2; tn++)
                acc[tm][tn] = __builtin_amdgcn_mfma_f32_16x16x32_bf16(
                    af[tm], bf[tn], acc[tm][tn], 0, 0, 0);
        __syncthreads();
    }

    // epilogue: D[row=lq*4+r][col=lr] per 16x16 tile
#pragma unroll
    for (int tm = 0; tm < 2; tm++) {
#pragma unroll
        for (int tn = 0; tn < 2; tn++) {
#pragma unroll
            for (int r = 0; r < 4; r++) {
                int mrow = bm + wm + tm * 16 + lq * 4 + r;
                int ncol = bn + wn + tn * 16 + lr;
                float vacc = acc[tm][tn][r];
                if (mode == 1) {
                    vacc = (res[(size_t)mrow * N + ncol] + vacc) * scale;
                } else if (mode == 2) {
                    vacc = gelu_exact(vacc + bias[ncol]);
                } else if (mode == 3) {
                    vacc = (res[(size_t)mrow * N + ncol] + vacc + bias[ncol]) * scale;
                }
                C[(size_t)mrow * N + ncol] = vacc;
            }
        }
    }
}

// ---------------------------------------------------------------------------
// Launch
// ---------------------------------------------------------------------------
extern "C" void kernel_launch(void* const* d_in, const int* in_sizes, int n_in,
                              void* d_out, int out_size, void* d_ws, size_t ws_size,
                              hipStream_t stream)
{
    const float* x        = (const float*)d_in[0];
    const float* rel_bias = (const float*)d_in[1];
    const float* wq       = (const float*)d_in[2];
    const float* wk       = (const float*)d_in[3];
    const float* wv       = (const float*)d_in[4];
    const float* w_out    = (const float*)d_in[5];
    const float* ln1_g    = (const float*)d_in[6];
    const float* ln1_b    = (const float*)d_in[7];
    const float* ln2_g    = (const float*)d_in[8];
    const float* ln2_b    = (const float*)d_in[9];
    const float* w1       = (const float*)d_in[10];
    const float* b1       = (const float*)d_in[11];
    const float* w2       = (const float*)d_in[12];
    const float* b2       = (const float*)d_in[13];
    float* out = (float*)d_out;
    float* ws  = (float*)d_ws;

    const size_t SZ = (size_t)ROWS * HID;  // 9,633,792 floats
    float* y1 = ws;              // LN1 output; later o / FFN hidden reuse
    float* q  = ws + SZ;
    float* k  = ws + 2 * SZ;
    float* v  = ws + 3 * SZ;
    float* o  = ws;              // reuse y1 region (dead after qkv)
    float* h  = ws;              // FFN hidden [0, 4SZ) — y1/q/k/v dead by then
    float* y2 = ws + 4 * SZ;
    // x1 (post-attention residual) lives in d_out.

    // 1. y1 = LN1(x)
    ln_kernel<<<ROWS, 256, 0, stream>>>(x, ln1_g, ln1_b, y1);

    // 2. q,k,v per-head projections
    qkv_kernel<<<ROWS, 768, 0, stream>>>(y1, wq, wk, wv, q, k, v);

    // 3. o = softmax((qk^T + bias)/sqrt(d)) @ v
    attn_kernel<<<dim3(NHEAD, NB), 256, 0, stream>>>(q, k, v, rel_bias, o);

    // 4. x1 = (x + o @ w_out^T) * RATE   -> d_out
    gemm_mfma_kernel<<<dim3(HID / 64, ROWS / 64), 256, 0, stream>>>(
        o, w_out, out, ROWS, HID, HID, /*mode=*/1, nullptr, x, RATE);

    // 5. y2 = LN2(x1)
    ln_kernel<<<ROWS, 256, 0, stream>>>(out, ln2_g, ln2_b, y2);

    // 6. h = gelu(y2 @ w1^T + b1)
    gemm_mfma_kernel<<<dim3(FFN / 64, ROWS / 64), 256, 0, stream>>>(
        y2, w1, h, ROWS, FFN, HID, /*mode=*/2, b1, nullptr, 1.0f);

    // 7. out = (x1 + h @ w2^T + b2) * RATE
    gemm_mfma_kernel<<<dim3(HID / 64, ROWS / 64), 256, 0, stream>>>(
        h, w2, out, ROWS, HID, FFN, /*mode=*/3, b2, out, RATE);
}

// Round 4
// 808.433 us; speedup vs baseline: 5.7728x; 1.4259x over previous
//
#include <hip/hip_runtime.h>
#include <math.h>

// Problem constants
#define NB    64            // batch
#define LSEQ  196           // H*W = 14*14
#define HID   768
#define NHEAD 24
#define HDIM  32
#define FFN   3072
#define ROWS  (NB * LSEQ)   // 12544
#define RATE  0.2f
#define LN_EPS 1e-5f

typedef unsigned short bf16_t;                              // raw bf16 bits
typedef short s16x8 __attribute__((ext_vector_type(8)));    // 8 bf16 (4 VGPRs)
typedef float f32x4 __attribute__((ext_vector_type(4)));    // MFMA accumulator

// fp32 -> bf16 round-to-nearest-even (bit pattern in ushort)
__device__ __forceinline__ unsigned short f2bf(float f) {
    unsigned u = __float_as_uint(f);
    unsigned r = u + 0x7fffu + ((u >> 16) & 1u);
    return (unsigned short)(r >> 16);
}

// async global->LDS, 16 B per lane, dest = wave-uniform base + lane*16
#define GLOAD_LDS16(g, l)                                                  \
    __builtin_amdgcn_global_load_lds(                                      \
        (const __attribute__((address_space(1))) void*)(g),                \
        (__attribute__((address_space(3))) void*)(l), 16, 0, 0)

// ---------------------------------------------------------------------------
// fp32 -> bf16 elementwise convert (weights). n4 = n/4.
// ---------------------------------------------------------------------------
__global__ __launch_bounds__(256) void cvt_bf16_kernel(
    const float* __restrict__ in, bf16_t* __restrict__ out, int n4)
{
    int i = blockIdx.x * 256 + threadIdx.x;
    if (i < n4) {
        float4 v = ((const float4*)in)[i];
        uint2 p;
        p.x = (unsigned)f2bf(v.x) | ((unsigned)f2bf(v.y) << 16);
        p.y = (unsigned)f2bf(v.z) | ((unsigned)f2bf(v.w) << 16);
        ((uint2*)out)[i] = p;
    }
}

// ---------------------------------------------------------------------------
// LayerNorm over last dim (768). One block (256 threads) per row.
// OBF: write bf16 instead of fp32.
// ---------------------------------------------------------------------------
template <bool OBF>
__global__ __launch_bounds__(256) void ln_kernel(
    const float* __restrict__ x, const float* __restrict__ g,
    const float* __restrict__ b, void* __restrict__ yv)
{
    int row = blockIdx.x;
    int tid = threadIdx.x;  // 0..255
    const float* xr = x + (size_t)row * HID;
    float v0 = xr[tid], v1 = xr[tid + 256], v2 = xr[tid + 512];
    __shared__ float rs[256], rs2[256];
    rs[tid]  = v0 + v1 + v2;
    rs2[tid] = v0 * v0 + v1 * v1 + v2 * v2;
    __syncthreads();
    for (int off = 128; off > 0; off >>= 1) {
        if (tid < off) { rs[tid] += rs[tid + off]; rs2[tid] += rs2[tid + off]; }
        __syncthreads();
    }
    float mean = rs[0] * (1.0f / HID);
    float var  = rs2[0] * (1.0f / HID) - mean * mean;
    float rstd = rsqrtf(var + LN_EPS);
    float o0 = (v0 - mean) * rstd * g[tid]       + b[tid];
    float o1 = (v1 - mean) * rstd * g[tid + 256] + b[tid + 256];
    float o2 = (v2 - mean) * rstd * g[tid + 512] + b[tid + 512];
    if (OBF) {
        bf16_t* yr = (bf16_t*)yv + (size_t)row * HID;
        yr[tid]       = f2bf(o0);
        yr[tid + 256] = f2bf(o1);
        yr[tid + 512] = f2bf(o2);
    } else {
        float* yr = (float*)yv + (size_t)row * HID;
        yr[tid] = o0; yr[tid + 256] = o1; yr[tid + 512] = o2;
    }
}

// ---------------------------------------------------------------------------
// Per-head QKV projection (heads share 32x32 weights). One block per row.
// ---------------------------------------------------------------------------
__global__ __launch_bounds__(768) void qkv_kernel(
    const float* __restrict__ y,
    const float* __restrict__ wq, const float* __restrict__ wk,
    const float* __restrict__ wv,
    float* __restrict__ q, float* __restrict__ k, float* __restrict__ v)
{
    int row = blockIdx.x;   // 0..12543
    int tid = threadIdx.x;  // 0..767
    __shared__ float xs[HID];
    __shared__ float wqs[32 * 33], wks[32 * 33], wvs[32 * 33];
    xs[tid] = y[(size_t)row * HID + tid];
    for (int i = tid; i < 1024; i += 768) {
        int e = i >> 5, d = i & 31;
        wqs[e * 33 + d] = wq[i];
        wks[e * 33 + d] = wk[i];
        wvs[e * 33 + d] = wv[i];
    }
    __syncthreads();
    int h = tid >> 5, e = tid & 31;
    const float* xv = xs + h * 32;
    float aq = 0.f, ak = 0.f, av = 0.f;
#pragma unroll
    for (int d = 0; d < 32; d++) {
        float xd = xv[d];
        aq += xd * wqs[e * 33 + d];
        ak += xd * wks[e * 33 + d];
        av += xd * wvs[e * 33 + d];
    }
    size_t o = (size_t)row * HID + tid;
    q[o] = aq; k[o] = ak; v[o] = av;
}

// ---------------------------------------------------------------------------
// Attention: one block (256 threads) per (h, n). K,V,bias staged in LDS once;
// thread t owns q-row t (t<196), online softmax over 196 keys, Q and O in
// registers. LDS reads are lockstep same-address broadcasts. Output bf16.
// ---------------------------------------------------------------------------
__global__ __launch_bounds__(256) void attn_kernel(
    const float* __restrict__ q, const float* __restrict__ k,
    const float* __restrict__ v, const float* __restrict__ rel_bias,
    bf16_t* __restrict__ o)
{
    int h = blockIdx.x;   // 0..23
    int n = blockIdx.y;   // 0..63
    int tid = threadIdx.x;

    __shared__ float Ks[LSEQ * 32];  // 25088 B
    __shared__ float Vs[LSEQ * 32];  // 25088 B
    __shared__ float bs[28 * 28];    //  3136 B

    size_t base = (size_t)n * LSEQ * HID + (size_t)h * HDIM;

    for (int i = tid; i < 1568; i += 256) {
        int r = i >> 3, c4 = i & 7;
        *(float4*)&Ks[r * 32 + c4 * 4] = *(const float4*)&k[base + (size_t)r * HID + c4 * 4];
        *(float4*)&Vs[r * 32 + c4 * 4] = *(const float4*)&v[base + (size_t)r * HID + c4 * 4];
    }
    for (int i = tid; i < 784; i += 256) bs[i] = rel_bias[i];
    __syncthreads();

    if (tid < LSEQ) {
        float4 q4[8];
        const float4* qg = (const float4*)&q[base + (size_t)tid * HID];
#pragma unroll
        for (int i = 0; i < 8; i++) q4[i] = qg[i];

        int qi_i = tid / 14, qi_j = tid - qi_i * 14;
        int bbase = (qi_i + 14) * 28 + (qi_j + 14);
        const float inv_sqrt_d = 0.17677669529663687f;  // 1/sqrt(32)

        float m = -INFINITY, l = 0.f;
        float4 o4[8] = {};

        for (int ip = 0; ip < 14; ip++) {
            int brow = bbase - ip * 28;
            for (int jp = 0; jp < 14; jp++) {
                int kk = ip * 14 + jp;
                const float4* kr = (const float4*)&Ks[kk * 32];
                float s = 0.f;
#pragma unroll
                for (int i = 0; i < 8; i++) {
                    s += q4[i].x * kr[i].x + q4[i].y * kr[i].y
                       + q4[i].z * kr[i].z + q4[i].w * kr[i].w;
                }
                s = (s + bs[brow - jp]) * inv_sqrt_d;
                if (s > m) {
                    float alpha = __expf(m - s);
                    l *= alpha;
#pragma unroll
                    for (int i = 0; i < 8; i++) {
                        o4[i].x *= alpha; o4[i].y *= alpha;
                        o4[i].z *= alpha; o4[i].w *= alpha;
                    }
                    m = s;
                }
                float p = __expf(s - m);
                l += p;
                const float4* vr = (const float4*)&Vs[kk * 32];
#pragma unroll
                for (int i = 0; i < 8; i++) {
                    o4[i].x += p * vr[i].x; o4[i].y += p * vr[i].y;
                    o4[i].z += p * vr[i].z; o4[i].w += p * vr[i].w;
                }
            }
        }
        float inv_l = 1.0f / l;
        unsigned pk[16];
#pragma unroll
        for (int i = 0; i < 8; i++) {
            float4 t = o4[i];
            pk[2 * i]     = (unsigned)f2bf(t.x * inv_l) | ((unsigned)f2bf(t.y * inv_l) << 16);
            pk[2 * i + 1] = (unsigned)f2bf(t.z * inv_l) | ((unsigned)f2bf(t.w * inv_l) << 16);
        }
        uint4* og = (uint4*)&o[base + (size_t)tid * HID];
#pragma unroll
        for (int j = 0; j < 4; j++) og[j] = ((uint4*)pk)[j];
    }
}

// ---------------------------------------------------------------------------
// bf16 MFMA GEMM, m97 structure: C[m,n] = sum_k A[m,k]*B[n,k], A:MxK bf16,
// B:NxK bf16 (torch Linear weight layout). 128x128 tile, BK=32, 256 threads
// = 4 waves, each wave a 64x64 quadrant = 4x4 MFMA tiles of 16x16x32.
// Staging via global_load_lds width=16 (wave-uniform LDS base + lane*16,
// unpadded 64 B rows). Epilogue modes:
//   1: C=(res+acc)*scale   2: C=gelu(acc+bias)   3: C=(res+acc+bias)*scale
// OBF: C is bf16.  M,N,K multiples of 128/128/32; no bound guards.
// ---------------------------------------------------------------------------
__device__ __forceinline__ float gelu_exact(float x) {
    return 0.5f * x * (1.0f + erff(x * 0.70710678118654752f));
}

template <int MODE, bool OBF>
__global__ __launch_bounds__(256) void gemm_mfma_128(
    const bf16_t* __restrict__ A, const bf16_t* __restrict__ B,
    void* __restrict__ Cv, int M, int N, int K,
    const float* __restrict__ bias, const float* __restrict__ res, float scale)
{
    __shared__ __align__(16) bf16_t As[128 * 32];  // 8 KiB, 64 B rows
    __shared__ __align__(16) bf16_t Bs[128 * 32];  // 8 KiB

    int tid  = threadIdx.x;           // 0..255
    int bm   = blockIdx.y * 128;
    int bn   = blockIdx.x * 128;
    int w    = tid >> 6;              // wave 0..3
    int lane = tid & 63;
    int wm = (w & 1) * 64;
    int wn = (w >> 1) * 64;
    int lr = lane & 15;               // m (A) / n (B) / col (C)
    int lq = lane >> 4;               // k-group (A/B) / row-group (C)

    // staging: wave w stages rows [w*32, w*32+32) of both tiles;
    // per instr: 16 rows x 64 B, lane supplies row (lane>>2), bytes (lane&3)*16
    int srow = (lane >> 2);
    int scb  = (lane & 3) * 16;
    const char* Ab = (const char*)A;
    const char* Bb = (const char*)B;

    f32x4 acc[4][4] = {};

    for (int k0 = 0; k0 < K; k0 += 32) {
#pragma unroll
        for (int j = 0; j < 2; j++) {
            int r = w * 32 + j * 16 + srow;
            GLOAD_LDS16(Ab + ((size_t)(bm + r) * K + k0) * 2 + scb,
                        &As[(w * 32 + j * 16) * 32]);
            GLOAD_LDS16(Bb + ((size_t)(bn + r) * K + k0) * 2 + scb,
                        &Bs[(w * 32 + j * 16) * 32]);
        }
        __syncthreads();

        s16x8 af[4], bf[4];
#pragma unroll
        for (int t = 0; t < 4; t++) {
            af[t] = *(const s16x8*)&As[(wm + t * 16 + lr) * 32 + lq * 8];
            bf[t] = *(const s16x8*)&Bs[(wn + t * 16 + lr) * 32 + lq * 8];
        }
#pragma unroll
        for (int tm = 0; tm < 4; tm++)
#pragma unroll
            for (int tn = 0; tn < 4; tn++)
                acc[tm][tn] = __builtin_amdgcn_mfma_f32_16x16x32_bf16(
                    af[tm], bf[tn], acc[tm][tn], 0, 0, 0);
        __syncthreads();
    }

    // epilogue: D[row=lq*4+r][col=lr] per 16x16 tile
#pragma unroll
    for (int tm = 0; tm < 4; tm++) {
#pragma unroll
        for (int tn = 0; tn < 4; tn++) {
#pragma unroll
            for (int r = 0; r < 4; r++) {
                int mrow = bm + wm + tm * 16 + lq * 4 + r;
                int ncol = bn + wn + tn * 16 + lr;
                float vacc = acc[tm][tn][r];
                if (MODE == 1) {
                    vacc = (res[(size_t)mrow * N + ncol] + vacc) * scale;
                } else if (MODE == 2) {
                    vacc = gelu_exact(vacc + bias[ncol]);
                } else if (MODE == 3) {
                    vacc = (res[(size_t)mrow * N + ncol] + vacc + bias[ncol]) * scale;
                }
                if (OBF) ((bf16_t*)Cv)[(size_t)mrow * N + ncol] = f2bf(vacc);
                else     ((float*)Cv)[(size_t)mrow * N + ncol] = vacc;
            }
        }
    }
}

// ---------------------------------------------------------------------------
// Launch
// ---------------------------------------------------------------------------
extern "C" void kernel_launch(void* const* d_in, const int* in_sizes, int n_in,
                              void* d_out, int out_size, void* d_ws, size_t ws_size,
                              hipStream_t stream)
{
    const float* x        = (const float*)d_in[0];
    const float* rel_bias = (const float*)d_in[1];
    const float* wq       = (const float*)d_in[2];
    const float* wk       = (const float*)d_in[3];
    const float* wv       = (const float*)d_in[4];
    const float* w_out    = (const float*)d_in[5];
    const float* ln1_g    = (const float*)d_in[6];
    const float* ln1_b    = (const float*)d_in[7];
    const float* ln2_g    = (const float*)d_in[8];
    const float* ln2_b    = (const float*)d_in[9];
    const float* w1       = (const float*)d_in[10];
    const float* b1       = (const float*)d_in[11];
    const float* w2       = (const float*)d_in[12];
    const float* b2       = (const float*)d_in[13];
    float* out = (float*)d_out;
    float* ws  = (float*)d_ws;

    const size_t SZ = (size_t)ROWS * HID;  // 9,633,792 floats
    // Region map (float units; lifetimes noted):
    //   [0, SZ)        y1 fp32 (dies after qkv); then o bf16 [0,SZ/2),
    //                  y2 bf16 [SZ/2, SZ)
    //   [SZ, 2SZ)      q fp32 (dies after attn);  } h bf16 [SZ,3SZ) after attn
    //   [2SZ, 3SZ)     k fp32 (dies after attn);  }
    //   [3SZ, 4SZ)     v fp32 (dies after attn)
    //   [4SZ, ...)     bf16 weights: wob 768x768, w1b 3072x768, w2b 768x3072
    float* y1 = ws;
    float* q  = ws + SZ;
    float* k  = ws + 2 * SZ;
    float* v  = ws + 3 * SZ;
    bf16_t* o_bf = (bf16_t*)ws;
    bf16_t* y2b  = (bf16_t*)(ws + SZ / 2);
    bf16_t* h    = (bf16_t*)(ws + SZ);
    bf16_t* wob  = (bf16_t*)(ws + 4 * SZ);
    bf16_t* w1b  = wob + (size_t)HID * HID;
    bf16_t* w2b  = w1b + (size_t)FFN * HID;

    // 0. one-time weight conversions (run every launch; ~10 us total)
    cvt_bf16_kernel<<<(HID * HID / 4 + 255) / 256, 256, 0, stream>>>(w_out, wob, HID * HID / 4);
    cvt_bf16_kernel<<<(FFN * HID / 4 + 255) / 256, 256, 0, stream>>>(w1, w1b, FFN * HID / 4);
    cvt_bf16_kernel<<<(FFN * HID / 4 + 255) / 256, 256, 0, stream>>>(w2, w2b, FFN * HID / 4);

    // 1. y1 = LN1(x)  (fp32, feeds qkv)
    ln_kernel<false><<<ROWS, 256, 0, stream>>>(x, ln1_g, ln1_b, y1);

    // 2. q,k,v per-head projections (fp32)
    qkv_kernel<<<ROWS, 768, 0, stream>>>(y1, wq, wk, wv, q, k, v);

    // 3. o = softmax((qk^T + bias)/sqrt(d)) @ v   (bf16 out)
    attn_kernel<<<dim3(NHEAD, NB), 256, 0, stream>>>(q, k, v, rel_bias, o_bf);

    // 4. x1 = (x + o @ w_out^T) * RATE   -> d_out (fp32)
    gemm_mfma_128<1, false><<<dim3(HID / 128, ROWS / 128), 256, 0, stream>>>(
        o_bf, wob, out, ROWS, HID, HID, nullptr, x, RATE);

    // 5. y2 = LN2(x1)  (bf16)
    ln_kernel<true><<<ROWS, 256, 0, stream>>>(out, ln2_g, ln2_b, y2b);

    // 6. h = gelu(y2 @ w1^T + b1)  (bf16)
    gemm_mfma_128<2, true><<<dim3(FFN / 128, ROWS / 128), 256, 0, stream>>>(
        y2b, w1b, h, ROWS, FFN, HID, b1, nullptr, 1.0f);

    // 7. out = (x1 + h @ w2^T + b2) * RATE  (fp32)
    gemm_mfma_128<3, false><<<dim3(HID / 128, ROWS / 128), 256, 0, stream>>>(
        h, w2b, out, ROWS, HID, FFN, b2, out, RATE);
}

// Round 5
// 604.279 us; speedup vs baseline: 7.7231x; 1.3378x over previous
//
#include <hip/hip_runtime.h>
#include <math.h>

// Problem constants
#define NB    64            // batch
#define LSEQ  196           // H*W = 14*14
#define HID   768
#define NHEAD 24
#define HDIM  32
#define FFN   3072
#define ROWS  (NB * LSEQ)   // 12544
#define RATE  0.2f
#define LN_EPS 1e-5f

typedef unsigned short bf16_t;                              // raw bf16 bits
typedef short s16x8 __attribute__((ext_vector_type(8)));    // 8 bf16 (4 VGPRs)
typedef float f32x4 __attribute__((ext_vector_type(4)));    // MFMA accumulator

// fp32 -> bf16 round-to-nearest-even (bit pattern in ushort)
__device__ __forceinline__ unsigned short f2bf(float f) {
    unsigned u = __float_as_uint(f);
    unsigned r = u + 0x7fffu + ((u >> 16) & 1u);
    return (unsigned short)(r >> 16);
}

// async global->LDS, 16 B per lane, dest = wave-uniform base + lane*16
#define GLOAD_LDS16(g, l)                                                  \
    __builtin_amdgcn_global_load_lds(                                      \
        (const __attribute__((address_space(1))) void*)(g),                \
        (__attribute__((address_space(3))) void*)(l), 16, 0, 0)

// ---------------------------------------------------------------------------
// fp32 -> bf16 elementwise convert (weights). n4 = n/4.
// ---------------------------------------------------------------------------
__global__ __launch_bounds__(256) void cvt_bf16_kernel(
    const float* __restrict__ in, bf16_t* __restrict__ out, int n4)
{
    int i = blockIdx.x * 256 + threadIdx.x;
    if (i < n4) {
        float4 v = ((const float4*)in)[i];
        uint2 p;
        p.x = (unsigned)f2bf(v.x) | ((unsigned)f2bf(v.y) << 16);
        p.y = (unsigned)f2bf(v.z) | ((unsigned)f2bf(v.w) << 16);
        ((uint2*)out)[i] = p;
    }
}

// ---------------------------------------------------------------------------
// LayerNorm over last dim (768). One block (256 threads) per row.
// OBF: write bf16 instead of fp32.
// ---------------------------------------------------------------------------
template <bool OBF>
__global__ __launch_bounds__(256) void ln_kernel(
    const float* __restrict__ x, const float* __restrict__ g,
    const float* __restrict__ b, void* __restrict__ yv)
{
    int row = blockIdx.x;
    int tid = threadIdx.x;  // 0..255
    const float* xr = x + (size_t)row * HID;
    float v0 = xr[tid], v1 = xr[tid + 256], v2 = xr[tid + 512];
    __shared__ float rs[256], rs2[256];
    rs[tid]  = v0 + v1 + v2;
    rs2[tid] = v0 * v0 + v1 * v1 + v2 * v2;
    __syncthreads();
    for (int off = 128; off > 0; off >>= 1) {
        if (tid < off) { rs[tid] += rs[tid + off]; rs2[tid] += rs2[tid + off]; }
        __syncthreads();
    }
    float mean = rs[0] * (1.0f / HID);
    float var  = rs2[0] * (1.0f / HID) - mean * mean;
    float rstd = rsqrtf(var + LN_EPS);
    float o0 = (v0 - mean) * rstd * g[tid]       + b[tid];
    float o1 = (v1 - mean) * rstd * g[tid + 256] + b[tid + 256];
    float o2 = (v2 - mean) * rstd * g[tid + 512] + b[tid + 512];
    if (OBF) {
        bf16_t* yr = (bf16_t*)yv + (size_t)row * HID;
        yr[tid]       = f2bf(o0);
        yr[tid + 256] = f2bf(o1);
        yr[tid + 512] = f2bf(o2);
    } else {
        float* yr = (float*)yv + (size_t)row * HID;
        yr[tid] = o0; yr[tid + 256] = o1; yr[tid + 512] = o2;
    }
}

// ---------------------------------------------------------------------------
// Per-head QKV projection (heads share 32x32 weights). One block per row.
// Outputs bf16 (feeds MFMA attention).
// ---------------------------------------------------------------------------
__global__ __launch_bounds__(768) void qkv_kernel(
    const float* __restrict__ y,
    const float* __restrict__ wq, const float* __restrict__ wk,
    const float* __restrict__ wv,
    bf16_t* __restrict__ q, bf16_t* __restrict__ k, bf16_t* __restrict__ v)
{
    int row = blockIdx.x;   // 0..12543
    int tid = threadIdx.x;  // 0..767
    __shared__ float xs[HID];
    __shared__ float wqs[32 * 33], wks[32 * 33], wvs[32 * 33];
    xs[tid] = y[(size_t)row * HID + tid];
    for (int i = tid; i < 1024; i += 768) {
        int e = i >> 5, d = i & 31;
        wqs[e * 33 + d] = wq[i];
        wks[e * 33 + d] = wk[i];
        wvs[e * 33 + d] = wv[i];
    }
    __syncthreads();
    int h = tid >> 5, e = tid & 31;
    const float* xv = xs + h * 32;
    float aq = 0.f, ak = 0.f, av = 0.f;
#pragma unroll
    for (int d = 0; d < 32; d++) {
        float xd = xv[d];
        aq += xd * wqs[e * 33 + d];
        ak += xd * wks[e * 33 + d];
        av += xd * wvs[e * 33 + d];
    }
    size_t o = (size_t)row * HID + tid;
    q[o] = f2bf(aq); k[o] = f2bf(ak); v[o] = f2bf(av);
}

// ---------------------------------------------------------------------------
// MFMA attention: one block (256 thr = 4 waves) per (h, n).
// Stage Q(208x32), K(224x32 zero-padded), V^T(32x224 stride 232), bias in LDS.
// Each wave owns q-tiles {w, w+4, ...} of 13. Per q-tile:
//   14 QK MFMAs (16x16x32; K-dim=32 is one chunk) -> S row in regs (56 VGPR)
//   bias + mask + exact 2-pass softmax (16-lane shuffle max/sum)
//   per 32-key chunk: P -> per-wave LDS (stride 40) -> A-frag -> 2 PV MFMAs
// Output o bf16, normalized at the end.
// ---------------------------------------------------------------------------
#define VT_S 232   // V^T row stride (bf16): 464 B, 16B-aligned, 2-way banks
#define P_S  40    // P row stride (bf16): 80 B

__global__ __launch_bounds__(256) void attn_mfma_kernel(
    const bf16_t* __restrict__ q, const bf16_t* __restrict__ k,
    const bf16_t* __restrict__ v, const float* __restrict__ rel_bias,
    bf16_t* __restrict__ o)
{
    int h = blockIdx.x;   // 0..23
    int n = blockIdx.y;   // 0..63
    int tid = threadIdx.x;
    int w = tid >> 6, lane = tid & 63;
    int lr = lane & 15;   // frag row/col index
    int lq = lane >> 4;   // quad

    __shared__ __align__(16) bf16_t Qs[208 * 32];        // 13312 B
    __shared__ __align__(16) bf16_t Ks[224 * 32];        // 14336 B
    __shared__ __align__(16) bf16_t Vt[32 * VT_S];       // 14848 B
    __shared__ float bsh[28 * 28];                       //  3136 B
    __shared__ __align__(16) bf16_t Ps[4][16 * P_S];     //  5120 B

    size_t base = (size_t)n * LSEQ * HID + (size_t)h * HDIM;  // bf16 elems

    // stage K (pad rows 196-223 = 0) and Q (pad rows 196-207 = 0)
    for (int i = tid; i < 224 * 4; i += 256) {
        int r = i >> 2, c = i & 3;
        uint4 kv = make_uint4(0, 0, 0, 0);
        if (r < 196) kv = *(const uint4*)&k[base + (size_t)r * HID + c * 8];
        *(uint4*)&Ks[r * 32 + c * 8] = kv;
        if (r < 208) {
            uint4 qv = make_uint4(0, 0, 0, 0);
            if (r < 196) qv = *(const uint4*)&q[base + (size_t)r * HID + c * 8];
            *(uint4*)&Qs[r * 32 + c * 8] = qv;
        }
    }
    // stage V transposed: Vt[d][key] = v[key][d]
    for (int i = tid; i < 196 * 16; i += 256) {
        int key = i >> 4, d2 = (i & 15) * 2;
        unsigned u = *(const unsigned*)&v[base + (size_t)key * HID + d2];
        Vt[d2 * VT_S + key]       = (bf16_t)(u & 0xffffu);
        Vt[(d2 + 1) * VT_S + key] = (bf16_t)(u >> 16);
    }
    for (int i = tid; i < 32 * 32; i += 256) {   // zero-pad keys 196..223
        int d = i >> 5, kp = i & 31;
        if (kp < 28) Vt[d * VT_S + 196 + kp] = 0;
    }
    for (int i = tid; i < 784; i += 256) bsh[i] = rel_bias[i];
    __syncthreads();

    const float inv_sqrt_d = 0.17677669529663687f;  // 1/sqrt(32)
    bf16_t* P = Ps[w];

    for (int qt = w; qt < 13; qt += 4) {
        s16x8 aQ = *(const s16x8*)&Qs[(qt * 16 + lr) * 32 + lq * 8];

        // per-lane row info (rows lq*4+r of this tile)
        int bb[4]; bool qvalid[4];
#pragma unroll
        for (int r = 0; r < 4; r++) {
            int qr = qt * 16 + lq * 4 + r;
            qvalid[r] = qr < LSEQ;
            int qq = qvalid[r] ? qr : 0;
            int qi = qq / 14, qj = qq - 14 * (qq / 14);
            bb[r] = (qi + 14) * 28 + (qj + 14);
        }

        // ---- QK phase: all 14 k-tiles into registers
        f32x4 sf[14];
#pragma unroll
        for (int kt = 0; kt < 14; kt++) {
            s16x8 bK = *(const s16x8*)&Ks[(kt * 16 + lr) * 32 + lq * 8];
            f32x4 z = {};
            sf[kt] = __builtin_amdgcn_mfma_f32_16x16x32_bf16(aQ, bK, z, 0, 0, 0);
        }
        // ---- bias + mask + scale
#pragma unroll
        for (int kt = 0; kt < 14; kt++) {
            int key = kt * 16 + lr;
            bool kv = key < LSEQ;
            int kk2 = kv ? key : 0;
            int ip = kk2 / 14, jp = kk2 - 14 * ip;
            int boff = ip * 28 + jp;
#pragma unroll
            for (int r = 0; r < 4; r++) {
                float val = (sf[kt][r] + bsh[bb[r] - boff]) * inv_sqrt_d;
                sf[kt][r] = kv ? val : -1e30f;
            }
        }
        // ---- row max (local over 14 tiles, then 16-lane shuffle)
        float mx[4];
#pragma unroll
        for (int r = 0; r < 4; r++) {
            float m = sf[0][r];
#pragma unroll
            for (int kt = 1; kt < 14; kt++) m = fmaxf(m, sf[kt][r]);
            mx[r] = m;
        }
#pragma unroll
        for (int d = 1; d < 16; d <<= 1)
#pragma unroll
            for (int r = 0; r < 4; r++)
                mx[r] = fmaxf(mx[r], __shfl_xor(mx[r], d));
        // ---- exp + row sum
        float sum[4] = {0.f, 0.f, 0.f, 0.f};
#pragma unroll
        for (int kt = 0; kt < 14; kt++)
#pragma unroll
            for (int r = 0; r < 4; r++) {
                float p = __expf(sf[kt][r] - mx[r]);
                sf[kt][r] = p;
                sum[r] += p;
            }
#pragma unroll
        for (int d = 1; d < 16; d <<= 1)
#pragma unroll
            for (int r = 0; r < 4; r++)
                sum[r] += __shfl_xor(sum[r], d);

        // ---- PV phase: per 32-key chunk, P through LDS, 2 MFMAs
        f32x4 oacc[2] = {};
#pragma unroll
        for (int kc = 0; kc < 7; kc++) {
#pragma unroll
            for (int r = 0; r < 4; r++) {
                P[(lq * 4 + r) * P_S + lr]      = f2bf(sf[2 * kc][r]);
                P[(lq * 4 + r) * P_S + 16 + lr] = f2bf(sf[2 * kc + 1][r]);
            }
            s16x8 aP = *(const s16x8*)&P[lr * P_S + lq * 8];
#pragma unroll
            for (int dt = 0; dt < 2; dt++) {
                s16x8 bV = *(const s16x8*)&Vt[(dt * 16 + lr) * VT_S + kc * 32 + lq * 8];
                oacc[dt] = __builtin_amdgcn_mfma_f32_16x16x32_bf16(aP, bV, oacc[dt], 0, 0, 0);
            }
        }
        // ---- write O (rows lq*4+r, cols dt*16+lr), normalize by 1/sum
#pragma unroll
        for (int r = 0; r < 4; r++) {
            if (qvalid[r]) {
                float inv_l = 1.0f / sum[r];
                size_t ob = base + (size_t)(qt * 16 + lq * 4 + r) * HID;
                o[ob + lr]      = f2bf(oacc[0][r] * inv_l);
                o[ob + 16 + lr] = f2bf(oacc[1][r] * inv_l);
            }
        }
    }
}

// ---------------------------------------------------------------------------
// bf16 MFMA GEMM, m97 structure: C[m,n] = sum_k A[m,k]*B[n,k], A:MxK bf16,
// B:NxK bf16 (torch Linear weight layout). 128x128 tile, BK=32, 256 threads
// = 4 waves, each wave a 64x64 quadrant = 4x4 MFMA tiles of 16x16x32.
// Staging via global_load_lds width=16. Epilogue modes:
//   1: C=(res+acc)*scale   2: C=gelu(acc+bias)   3: C=(res+acc+bias)*scale
// OBF: C is bf16.  M,N,K multiples of 128/128/32; no bound guards.
// ---------------------------------------------------------------------------
__device__ __forceinline__ float gelu_exact(float x) {
    return 0.5f * x * (1.0f + erff(x * 0.70710678118654752f));
}

template <int MODE, bool OBF>
__global__ __launch_bounds__(256) void gemm_mfma_128(
    const bf16_t* __restrict__ A, const bf16_t* __restrict__ B,
    void* __restrict__ Cv, int M, int N, int K,
    const float* __restrict__ bias, const float* __restrict__ res, float scale)
{
    __shared__ __align__(16) bf16_t As[128 * 32];  // 8 KiB, 64 B rows
    __shared__ __align__(16) bf16_t Bs[128 * 32];  // 8 KiB

    int tid  = threadIdx.x;           // 0..255
    int bm   = blockIdx.y * 128;
    int bn   = blockIdx.x * 128;
    int w    = tid >> 6;              // wave 0..3
    int lane = tid & 63;
    int wm = (w & 1) * 64;
    int wn = (w >> 1) * 64;
    int lr = lane & 15;               // m (A) / n (B) / col (C)
    int lq = lane >> 4;               // k-group (A/B) / row-group (C)

    int srow = (lane >> 2);
    int scb  = (lane & 3) * 16;
    const char* Ab = (const char*)A;
    const char* Bb = (const char*)B;

    f32x4 acc[4][4] = {};

    for (int k0 = 0; k0 < K; k0 += 32) {
#pragma unroll
        for (int j = 0; j < 2; j++) {
            int r = w * 32 + j * 16 + srow;
            GLOAD_LDS16(Ab + ((size_t)(bm + r) * K + k0) * 2 + scb,
                        &As[(w * 32 + j * 16) * 32]);
            GLOAD_LDS16(Bb + ((size_t)(bn + r) * K + k0) * 2 + scb,
                        &Bs[(w * 32 + j * 16) * 32]);
        }
        __syncthreads();

        s16x8 af[4], bf[4];
#pragma unroll
        for (int t = 0; t < 4; t++) {
            af[t] = *(const s16x8*)&As[(wm + t * 16 + lr) * 32 + lq * 8];
            bf[t] = *(const s16x8*)&Bs[(wn + t * 16 + lr) * 32 + lq * 8];
        }
#pragma unroll
        for (int tm = 0; tm < 4; tm++)
#pragma unroll
            for (int tn = 0; tn < 4; tn++)
                acc[tm][tn] = __builtin_amdgcn_mfma_f32_16x16x32_bf16(
                    af[tm], bf[tn], acc[tm][tn], 0, 0, 0);
        __syncthreads();
    }

#pragma unroll
    for (int tm = 0; tm < 4; tm++) {
#pragma unroll
        for (int tn = 0; tn < 4; tn++) {
#pragma unroll
            for (int r = 0; r < 4; r++) {
                int mrow = bm + wm + tm * 16 + lq * 4 + r;
                int ncol = bn + wn + tn * 16 + lr;
                float vacc = acc[tm][tn][r];
                if (MODE == 1) {
                    vacc = (res[(size_t)mrow * N + ncol] + vacc) * scale;
                } else if (MODE == 2) {
                    vacc = gelu_exact(vacc + bias[ncol]);
                } else if (MODE == 3) {
                    vacc = (res[(size_t)mrow * N + ncol] + vacc + bias[ncol]) * scale;
                }
                if (OBF) ((bf16_t*)Cv)[(size_t)mrow * N + ncol] = f2bf(vacc);
                else     ((float*)Cv)[(size_t)mrow * N + ncol] = vacc;
            }
        }
    }
}

// ---------------------------------------------------------------------------
// Launch
// ---------------------------------------------------------------------------
extern "C" void kernel_launch(void* const* d_in, const int* in_sizes, int n_in,
                              void* d_out, int out_size, void* d_ws, size_t ws_size,
                              hipStream_t stream)
{
    const float* x        = (const float*)d_in[0];
    const float* rel_bias = (const float*)d_in[1];
    const float* wq       = (const float*)d_in[2];
    const float* wk       = (const float*)d_in[3];
    const float* wv       = (const float*)d_in[4];
    const float* w_out    = (const float*)d_in[5];
    const float* ln1_g    = (const float*)d_in[6];
    const float* ln1_b    = (const float*)d_in[7];
    const float* ln2_g    = (const float*)d_in[8];
    const float* ln2_b    = (const float*)d_in[9];
    const float* w1       = (const float*)d_in[10];
    const float* b1       = (const float*)d_in[11];
    const float* w2       = (const float*)d_in[12];
    const float* b2       = (const float*)d_in[13];
    float* out = (float*)d_out;
    float* ws  = (float*)d_ws;

    const size_t SZ = (size_t)ROWS * HID;  // 9,633,792 floats
    // Region map (float units):
    //   [0, SZ)      y1 fp32 (dies after qkv); then o bf16 [0,SZ/2),
    //                y2 bf16 [SZ/2, SZ)
    //   [SZ, 1.5SZ)  q bf16 (dies after attn)   } h bf16 [SZ,3SZ) after attn
    //   [2SZ, 2.5SZ) k bf16 (dies after attn)   }
    //   [3SZ, 3.5SZ) v bf16 (dies after attn)   (h ends exactly at 3SZ)
    //   [4SZ, ...)   bf16 weights: wob 768x768, w1b 3072x768, w2b 768x3072
    float* y1 = ws;
    bf16_t* q_bf = (bf16_t*)(ws + SZ);
    bf16_t* k_bf = (bf16_t*)(ws + 2 * SZ);
    bf16_t* v_bf = (bf16_t*)(ws + 3 * SZ);
    bf16_t* o_bf = (bf16_t*)ws;
    bf16_t* y2b  = (bf16_t*)(ws + SZ / 2);
    bf16_t* h    = (bf16_t*)(ws + SZ);
    bf16_t* wob  = (bf16_t*)(ws + 4 * SZ);
    bf16_t* w1b  = wob + (size_t)HID * HID;
    bf16_t* w2b  = w1b + (size_t)FFN * HID;

    // 0. weight conversions
    cvt_bf16_kernel<<<(HID * HID / 4 + 255) / 256, 256, 0, stream>>>(w_out, wob, HID * HID / 4);
    cvt_bf16_kernel<<<(FFN * HID / 4 + 255) / 256, 256, 0, stream>>>(w1, w1b, FFN * HID / 4);
    cvt_bf16_kernel<<<(FFN * HID / 4 + 255) / 256, 256, 0, stream>>>(w2, w2b, FFN * HID / 4);

    // 1. y1 = LN1(x)  (fp32, feeds qkv)
    ln_kernel<false><<<ROWS, 256, 0, stream>>>(x, ln1_g, ln1_b, y1);

    // 2. q,k,v per-head projections (bf16 out)
    qkv_kernel<<<ROWS, 768, 0, stream>>>(y1, wq, wk, wv, q_bf, k_bf, v_bf);

    // 3. o = softmax((qk^T + bias)/sqrt(d)) @ v   (MFMA, bf16 out)
    attn_mfma_kernel<<<dim3(NHEAD, NB), 256, 0, stream>>>(q_bf, k_bf, v_bf, rel_bias, o_bf);

    // 4. x1 = (x + o @ w_out^T) * RATE   -> d_out (fp32)
    gemm_mfma_128<1, false><<<dim3(HID / 128, ROWS / 128), 256, 0, stream>>>(
        o_bf, wob, out, ROWS, HID, HID, nullptr, x, RATE);

    // 5. y2 = LN2(x1)  (bf16)
    ln_kernel<true><<<ROWS, 256, 0, stream>>>(out, ln2_g, ln2_b, y2b);

    // 6. h = gelu(y2 @ w1^T + b1)  (bf16)
    gemm_mfma_128<2, true><<<dim3(FFN / 128, ROWS / 128), 256, 0, stream>>>(
        y2b, w1b, h, ROWS, FFN, HID, b1, nullptr, 1.0f);

    // 7. out = (x1 + h @ w2^T + b2) * RATE  (fp32)
    gemm_mfma_128<3, false><<<dim3(HID / 128, ROWS / 128), 256, 0, stream>>>(
        h, w2b, out, ROWS, HID, FFN, b2, out, RATE);
}

// Round 6
// 579.473 us; speedup vs baseline: 8.0537x; 1.0428x over previous
//
#include <hip/hip_runtime.h>
#include <math.h>

// Problem constants
#define NB    64            // batch
#define LSEQ  196           // H*W = 14*14
#define HID   768
#define NHEAD 24
#define HDIM  32
#define FFN   3072
#define ROWS  (NB * LSEQ)   // 12544
#define RATE  0.2f
#define LN_EPS 1e-5f

typedef unsigned short bf16_t;                              // raw bf16 bits
typedef short s16x8 __attribute__((ext_vector_type(8)));    // 8 bf16 (4 VGPRs)
typedef float f32x4 __attribute__((ext_vector_type(4)));    // MFMA accumulator

// fp32 -> bf16 round-to-nearest-even (bit pattern in ushort)
__device__ __forceinline__ unsigned short f2bf(float f) {
    unsigned u = __float_as_uint(f);
    unsigned r = u + 0x7fffu + ((u >> 16) & 1u);
    return (unsigned short)(r >> 16);
}

// async global->LDS, 16 B per lane, dest = wave-uniform base + lane*16
#define GLOAD_LDS16(g, l)                                                  \
    __builtin_amdgcn_global_load_lds(                                      \
        (const __attribute__((address_space(1))) void*)(g),                \
        (__attribute__((address_space(3))) void*)(l), 16, 0, 0)

// ---------------------------------------------------------------------------
// fp32 -> bf16 elementwise convert (weights). n4 = n/4.
// ---------------------------------------------------------------------------
__global__ __launch_bounds__(256) void cvt_bf16_kernel(
    const float* __restrict__ in, bf16_t* __restrict__ out, int n4)
{
    int i = blockIdx.x * 256 + threadIdx.x;
    if (i < n4) {
        float4 v = ((const float4*)in)[i];
        uint2 p;
        p.x = (unsigned)f2bf(v.x) | ((unsigned)f2bf(v.y) << 16);
        p.y = (unsigned)f2bf(v.z) | ((unsigned)f2bf(v.w) << 16);
        ((uint2*)out)[i] = p;
    }
}

// ---------------------------------------------------------------------------
// LayerNorm over last dim (768). One block (256 threads) per row. bf16 out.
// (Used for LN2 only; LN1 is fused into ln_qkv_kernel.)
// ---------------------------------------------------------------------------
__global__ __launch_bounds__(256) void ln_kernel(
    const float* __restrict__ x, const float* __restrict__ g,
    const float* __restrict__ b, bf16_t* __restrict__ yv)
{
    int row = blockIdx.x;
    int tid = threadIdx.x;  // 0..255
    const float* xr = x + (size_t)row * HID;
    float v0 = xr[tid], v1 = xr[tid + 256], v2 = xr[tid + 512];
    __shared__ float rs[256], rs2[256];
    rs[tid]  = v0 + v1 + v2;
    rs2[tid] = v0 * v0 + v1 * v1 + v2 * v2;
    __syncthreads();
    for (int off = 128; off > 0; off >>= 1) {
        if (tid < off) { rs[tid] += rs[tid + off]; rs2[tid] += rs2[tid + off]; }
        __syncthreads();
    }
    float mean = rs[0] * (1.0f / HID);
    float var  = rs2[0] * (1.0f / HID) - mean * mean;
    float rstd = rsqrtf(var + LN_EPS);
    bf16_t* yr = yv + (size_t)row * HID;
    yr[tid]       = f2bf((v0 - mean) * rstd * g[tid]       + b[tid]);
    yr[tid + 256] = f2bf((v1 - mean) * rstd * g[tid + 256] + b[tid + 256]);
    yr[tid + 512] = f2bf((v2 - mean) * rstd * g[tid + 512] + b[tid + 512]);
}

// ---------------------------------------------------------------------------
// Fused LN1 + per-head QKV projection. One block (768 thr = 12 waves) per
// 4 rows; 32x32 weights staged once per block. Per row: wave shuffle-reduce
// for mean/var, cross-wave via 12 LDS partials; normalized row goes to LDS
// (each wave reads only its own 64-elem region -> no barrier needed there).
// Outputs bf16 q/k/v.
// ---------------------------------------------------------------------------
__global__ __launch_bounds__(768) void ln_qkv_kernel(
    const float* __restrict__ x, const float* __restrict__ g,
    const float* __restrict__ b,
    const float* __restrict__ wq, const float* __restrict__ wk,
    const float* __restrict__ wv,
    bf16_t* __restrict__ q, bf16_t* __restrict__ k, bf16_t* __restrict__ v)
{
    int tid = threadIdx.x;  // 0..767
    int wv_ = tid >> 6, lane = tid & 63;
    __shared__ float wqs[32 * 33], wks[32 * 33], wvs[32 * 33];
    __shared__ float xs[HID];
    __shared__ float reds[12], reds2[12];
    for (int i = tid; i < 1024; i += 768) {
        int e = i >> 5, d = i & 31;
        wqs[e * 33 + d] = wq[i];
        wks[e * 33 + d] = wk[i];
        wvs[e * 33 + d] = wv[i];
    }
    int h = tid >> 5, e = tid & 31;
    float gg = g[tid], bb = b[tid];

    for (int rr = 0; rr < 4; rr++) {
        int row = blockIdx.x * 4 + rr;
        float xv = x[(size_t)row * HID + tid];
        float s = xv, s2 = xv * xv;
#pragma unroll
        for (int d = 32; d > 0; d >>= 1) {
            s  += __shfl_down(s, d);
            s2 += __shfl_down(s2, d);
        }
        __syncthreads();   // reds reuse from prev iter; also covers wqs staging
        if (lane == 0) { reds[wv_] = s; reds2[wv_] = s2; }
        __syncthreads();
        float ts = 0.f, ts2 = 0.f;
#pragma unroll
        for (int i = 0; i < 12; i++) { ts += reds[i]; ts2 += reds2[i]; }
        float mean = ts * (1.0f / HID);
        float var  = ts2 * (1.0f / HID) - mean * mean;
        float rstd = rsqrtf(var + LN_EPS);
        xs[tid] = (xv - mean) * rstd * gg + bb;
        // xs region read below is written by this wave's own lanes -> in-order
        const float* xvp = xs + h * 32;
        float aq = 0.f, ak = 0.f, av = 0.f;
#pragma unroll
        for (int d = 0; d < 32; d++) {
            float xd = xvp[d];
            aq += xd * wqs[e * 33 + d];
            ak += xd * wks[e * 33 + d];
            av += xd * wvs[e * 33 + d];
        }
        size_t o = (size_t)row * HID + tid;
        q[o] = f2bf(aq); k[o] = f2bf(ak); v[o] = f2bf(av);
    }
}

// ---------------------------------------------------------------------------
// MFMA attention: one block (256 thr = 4 waves) per (h, n). Unchanged from
// round 5 (not the bottleneck).
// ---------------------------------------------------------------------------
#define VT_S 232   // V^T row stride (bf16)
#define P_S  40    // P row stride (bf16)

__global__ __launch_bounds__(256) void attn_mfma_kernel(
    const bf16_t* __restrict__ q, const bf16_t* __restrict__ k,
    const bf16_t* __restrict__ v, const float* __restrict__ rel_bias,
    bf16_t* __restrict__ o)
{
    int h = blockIdx.x;   // 0..23
    int n = blockIdx.y;   // 0..63
    int tid = threadIdx.x;
    int w = tid >> 6, lane = tid & 63;
    int lr = lane & 15;
    int lq = lane >> 4;

    __shared__ __align__(16) bf16_t Qs[208 * 32];
    __shared__ __align__(16) bf16_t Ks[224 * 32];
    __shared__ __align__(16) bf16_t Vt[32 * VT_S];
    __shared__ float bsh[28 * 28];
    __shared__ __align__(16) bf16_t Ps[4][16 * P_S];

    size_t base = (size_t)n * LSEQ * HID + (size_t)h * HDIM;

    for (int i = tid; i < 224 * 4; i += 256) {
        int r = i >> 2, c = i & 3;
        uint4 kv = make_uint4(0, 0, 0, 0);
        if (r < 196) kv = *(const uint4*)&k[base + (size_t)r * HID + c * 8];
        *(uint4*)&Ks[r * 32 + c * 8] = kv;
        if (r < 208) {
            uint4 qv = make_uint4(0, 0, 0, 0);
            if (r < 196) qv = *(const uint4*)&q[base + (size_t)r * HID + c * 8];
            *(uint4*)&Qs[r * 32 + c * 8] = qv;
        }
    }
    for (int i = tid; i < 196 * 16; i += 256) {
        int key = i >> 4, d2 = (i & 15) * 2;
        unsigned u = *(const unsigned*)&v[base + (size_t)key * HID + d2];
        Vt[d2 * VT_S + key]       = (bf16_t)(u & 0xffffu);
        Vt[(d2 + 1) * VT_S + key] = (bf16_t)(u >> 16);
    }
    for (int i = tid; i < 32 * 32; i += 256) {
        int d = i >> 5, kp = i & 31;
        if (kp < 28) Vt[d * VT_S + 196 + kp] = 0;
    }
    for (int i = tid; i < 784; i += 256) bsh[i] = rel_bias[i];
    __syncthreads();

    const float inv_sqrt_d = 0.17677669529663687f;
    bf16_t* P = Ps[w];

    for (int qt = w; qt < 13; qt += 4) {
        s16x8 aQ = *(const s16x8*)&Qs[(qt * 16 + lr) * 32 + lq * 8];

        int bb[4]; bool qvalid[4];
#pragma unroll
        for (int r = 0; r < 4; r++) {
            int qr = qt * 16 + lq * 4 + r;
            qvalid[r] = qr < LSEQ;
            int qq = qvalid[r] ? qr : 0;
            int qi = qq / 14, qj = qq - 14 * (qq / 14);
            bb[r] = (qi + 14) * 28 + (qj + 14);
        }

        f32x4 sf[14];
#pragma unroll
        for (int kt = 0; kt < 14; kt++) {
            s16x8 bK = *(const s16x8*)&Ks[(kt * 16 + lr) * 32 + lq * 8];
            f32x4 z = {};
            sf[kt] = __builtin_amdgcn_mfma_f32_16x16x32_bf16(aQ, bK, z, 0, 0, 0);
        }
#pragma unroll
        for (int kt = 0; kt < 14; kt++) {
            int key = kt * 16 + lr;
            bool kv = key < LSEQ;
            int kk2 = kv ? key : 0;
            int ip = kk2 / 14, jp = kk2 - 14 * ip;
            int boff = ip * 28 + jp;
#pragma unroll
            for (int r = 0; r < 4; r++) {
                float val = (sf[kt][r] + bsh[bb[r] - boff]) * inv_sqrt_d;
                sf[kt][r] = kv ? val : -1e30f;
            }
        }
        float mx[4];
#pragma unroll
        for (int r = 0; r < 4; r++) {
            float m = sf[0][r];
#pragma unroll
            for (int kt = 1; kt < 14; kt++) m = fmaxf(m, sf[kt][r]);
            mx[r] = m;
        }
#pragma unroll
        for (int d = 1; d < 16; d <<= 1)
#pragma unroll
            for (int r = 0; r < 4; r++)
                mx[r] = fmaxf(mx[r], __shfl_xor(mx[r], d));
        float sum[4] = {0.f, 0.f, 0.f, 0.f};
#pragma unroll
        for (int kt = 0; kt < 14; kt++)
#pragma unroll
            for (int r = 0; r < 4; r++) {
                float p = __expf(sf[kt][r] - mx[r]);
                sf[kt][r] = p;
                sum[r] += p;
            }
#pragma unroll
        for (int d = 1; d < 16; d <<= 1)
#pragma unroll
            for (int r = 0; r < 4; r++)
                sum[r] += __shfl_xor(sum[r], d);

        f32x4 oacc[2] = {};
#pragma unroll
        for (int kc = 0; kc < 7; kc++) {
#pragma unroll
            for (int r = 0; r < 4; r++) {
                P[(lq * 4 + r) * P_S + lr]      = f2bf(sf[2 * kc][r]);
                P[(lq * 4 + r) * P_S + 16 + lr] = f2bf(sf[2 * kc + 1][r]);
            }
            s16x8 aP = *(const s16x8*)&P[lr * P_S + lq * 8];
#pragma unroll
            for (int dt = 0; dt < 2; dt++) {
                s16x8 bV = *(const s16x8*)&Vt[(dt * 16 + lr) * VT_S + kc * 32 + lq * 8];
                oacc[dt] = __builtin_amdgcn_mfma_f32_16x16x32_bf16(aP, bV, oacc[dt], 0, 0, 0);
            }
        }
#pragma unroll
        for (int r = 0; r < 4; r++) {
            if (qvalid[r]) {
                float inv_l = 1.0f / sum[r];
                size_t ob = base + (size_t)(qt * 16 + lq * 4 + r) * HID;
                o[ob + lr]      = f2bf(oacc[0][r] * inv_l);
                o[ob + 16 + lr] = f2bf(oacc[1][r] * inv_l);
            }
        }
    }
}

// ---------------------------------------------------------------------------
// bf16 MFMA GEMM v2: C[m,n] = sum_k A[m,k]*B[n,k]. 128x128 tile, BK=64,
// 256 threads = 4 waves (64x64 quadrant each, 4x4 MFMA tiles of 16x16x32,
// 2 k-chunks per LDS tile). XOR-swizzled LDS layout: physical 16B chunk
// p = c_log ^ (row&7); staging permutes the *global* source per lane
// (global_load_lds dest is lane-fixed), fragment reads land 2-way on banks.
// 1D grid, XCD-aware swizzle: same-m blocks dispatched 8 apart -> same XCD.
// Epilogue: 1: C=(res+acc)*scale  2: C=gelu(acc+bias)  3: C=(res+acc+bias)*scale
// M,N mult of 128; K mult of 64.
// ---------------------------------------------------------------------------
__device__ __forceinline__ float gelu_exact(float x) {
    return 0.5f * x * (1.0f + erff(x * 0.70710678118654752f));
}

template <int MODE, bool OBF>
__global__ __launch_bounds__(256) void gemm_mfma_128(
    const bf16_t* __restrict__ A, const bf16_t* __restrict__ B,
    void* __restrict__ Cv, int M, int N, int K,
    const float* __restrict__ bias, const float* __restrict__ res, float scale)
{
    __shared__ __align__(16) bf16_t As[128 * 64];  // 16 KiB
    __shared__ __align__(16) bf16_t Bs[128 * 64];  // 16 KiB

    int tid = threadIdx.x;
    // XCD-aware block swizzle: linear id -> (m,n) with same-m blocks 8 apart
    int mb = M >> 7, nb = N >> 7;
    int gblk = blockIdx.x;
    int full = mb & ~7;
    int gfull = full * nb;
    int m_, n_;
    if (gblk < gfull) {
        int sg = gblk / (8 * nb), u = gblk - sg * (8 * nb);
        m_ = sg * 8 + (u & 7); n_ = u >> 3;
    } else {
        int u = gblk - gfull, rem = mb - full;
        m_ = full + u % rem; n_ = u / rem;
    }
    int bm = m_ << 7, bn = n_ << 7;

    int w    = tid >> 6;              // wave 0..3
    int lane = tid & 63;
    int wm = (w & 1) * 64;
    int wn = (w >> 1) * 64;
    int lr = lane & 15;               // m (A) / n (B) / col (C)
    int lq = lane >> 4;               // k-group (A/B) / row-group (C)

    // staging: instr j covers 8 rows x 128 B; lane -> row lane>>3,
    // physical chunk lane&7 holds logical chunk (lane&7)^(lane>>3)
    int srowl = lane >> 3;                    // 0..7
    int scb   = ((lane & 7) ^ srowl) * 16;    // swizzled source byte offset
    const char* Ab = (const char*)A;
    const char* Bb = (const char*)B;

    f32x4 acc[4][4] = {};

    for (int k0 = 0; k0 < K; k0 += 64) {
#pragma unroll
        for (int j = 0; j < 4; j++) {
            int rb = w * 32 + j * 8;
            int r  = rb + srowl;
            GLOAD_LDS16(Ab + ((size_t)(bm + r) * K + k0) * 2 + scb, &As[rb * 64]);
            GLOAD_LDS16(Bb + ((size_t)(bn + r) * K + k0) * 2 + scb, &Bs[rb * 64]);
        }
        __syncthreads();

        int sw = lr & 7;
#pragma unroll
        for (int kc = 0; kc < 2; kc++) {
            s16x8 af[4], bf[4];
#pragma unroll
            for (int t = 0; t < 4; t++) {
                int cof = (((kc << 2) | lq) ^ sw) * 8;
                af[t] = *(const s16x8*)&As[(wm + t * 16 + lr) * 64 + cof];
                bf[t] = *(const s16x8*)&Bs[(wn + t * 16 + lr) * 64 + cof];
            }
#pragma unroll
            for (int tm = 0; tm < 4; tm++)
#pragma unroll
                for (int tn = 0; tn < 4; tn++)
                    acc[tm][tn] = __builtin_amdgcn_mfma_f32_16x16x32_bf16(
                        af[tm], bf[tn], acc[tm][tn], 0, 0, 0);
        }
        __syncthreads();
    }

#pragma unroll
    for (int tm = 0; tm < 4; tm++) {
#pragma unroll
        for (int tn = 0; tn < 4; tn++) {
#pragma unroll
            for (int r = 0; r < 4; r++) {
                int mrow = bm + wm + tm * 16 + lq * 4 + r;
                int ncol = bn + wn + tn * 16 + lr;
                float vacc = acc[tm][tn][r];
                if (MODE == 1) {
                    vacc = (res[(size_t)mrow * N + ncol] + vacc) * scale;
                } else if (MODE == 2) {
                    vacc = gelu_exact(vacc + bias[ncol]);
                } else if (MODE == 3) {
                    vacc = (res[(size_t)mrow * N + ncol] + vacc + bias[ncol]) * scale;
                }
                if (OBF) ((bf16_t*)Cv)[(size_t)mrow * N + ncol] = f2bf(vacc);
                else     ((float*)Cv)[(size_t)mrow * N + ncol] = vacc;
            }
        }
    }
}

// ---------------------------------------------------------------------------
// Launch
// ---------------------------------------------------------------------------
extern "C" void kernel_launch(void* const* d_in, const int* in_sizes, int n_in,
                              void* d_out, int out_size, void* d_ws, size_t ws_size,
                              hipStream_t stream)
{
    const float* x        = (const float*)d_in[0];
    const float* rel_bias = (const float*)d_in[1];
    const float* wq       = (const float*)d_in[2];
    const float* wk       = (const float*)d_in[3];
    const float* wv       = (const float*)d_in[4];
    const float* w_out    = (const float*)d_in[5];
    const float* ln1_g    = (const float*)d_in[6];
    const float* ln1_b    = (const float*)d_in[7];
    const float* ln2_g    = (const float*)d_in[8];
    const float* ln2_b    = (const float*)d_in[9];
    const float* w1       = (const float*)d_in[10];
    const float* b1       = (const float*)d_in[11];
    const float* w2       = (const float*)d_in[12];
    const float* b2       = (const float*)d_in[13];
    float* out = (float*)d_out;
    float* ws  = (float*)d_ws;

    const size_t SZ = (size_t)ROWS * HID;  // 9,633,792 floats
    // Region map (float units):
    //   [0, SZ/2)    o bf16; y2 bf16 [SZ/2, SZ)
    //   [SZ, 1.5SZ)  q bf16 (dies after attn)   } h bf16 [SZ,3SZ) after attn
    //   [2SZ, 2.5SZ) k bf16 (dies after attn)   }
    //   [3SZ, 3.5SZ) v bf16 (dies after attn)
    //   [4SZ, ...)   bf16 weights: wob 768x768, w1b 3072x768, w2b 768x3072
    bf16_t* q_bf = (bf16_t*)(ws + SZ);
    bf16_t* k_bf = (bf16_t*)(ws + 2 * SZ);
    bf16_t* v_bf = (bf16_t*)(ws + 3 * SZ);
    bf16_t* o_bf = (bf16_t*)ws;
    bf16_t* y2b  = (bf16_t*)(ws + SZ / 2);
    bf16_t* h    = (bf16_t*)(ws + SZ);
    bf16_t* wob  = (bf16_t*)(ws + 4 * SZ);
    bf16_t* w1b  = wob + (size_t)HID * HID;
    bf16_t* w2b  = w1b + (size_t)FFN * HID;

    // 0. weight conversions
    cvt_bf16_kernel<<<(HID * HID / 4 + 255) / 256, 256, 0, stream>>>(w_out, wob, HID * HID / 4);
    cvt_bf16_kernel<<<(FFN * HID / 4 + 255) / 256, 256, 0, stream>>>(w1, w1b, FFN * HID / 4);
    cvt_bf16_kernel<<<(FFN * HID / 4 + 255) / 256, 256, 0, stream>>>(w2, w2b, FFN * HID / 4);

    // 1+2. fused LN1 + q,k,v per-head projections (bf16 out)
    ln_qkv_kernel<<<ROWS / 4, 768, 0, stream>>>(x, ln1_g, ln1_b, wq, wk, wv,
                                                q_bf, k_bf, v_bf);

    // 3. o = softmax((qk^T + bias)/sqrt(d)) @ v   (MFMA, bf16 out)
    attn_mfma_kernel<<<dim3(NHEAD, NB), 256, 0, stream>>>(q_bf, k_bf, v_bf, rel_bias, o_bf);

    // 4. x1 = (x + o @ w_out^T) * RATE   -> d_out (fp32)
    gemm_mfma_128<1, false><<<(ROWS / 128) * (HID / 128), 256, 0, stream>>>(
        o_bf, wob, out, ROWS, HID, HID, nullptr, x, RATE);

    // 5. y2 = LN2(x1)  (bf16)
    ln_kernel<<<ROWS, 256, 0, stream>>>(out, ln2_g, ln2_b, y2b);

    // 6. h = gelu(y2 @ w1^T + b1)  (bf16)
    gemm_mfma_128<2, true><<<(ROWS / 128) * (FFN / 128), 256, 0, stream>>>(
        y2b, w1b, h, ROWS, FFN, HID, b1, nullptr, 1.0f);

    // 7. out = (x1 + h @ w2^T + b2) * RATE  (fp32)
    gemm_mfma_128<3, false><<<(ROWS / 128) * (HID / 128), 256, 0, stream>>>(
        h, w2b, out, ROWS, HID, FFN, b2, out, RATE);
}

// Round 7
// 532.837 us; speedup vs baseline: 8.7586x; 1.0875x over previous
//
#include <hip/hip_runtime.h>
#include <math.h>

// Problem constants
#define NB    64            // batch
#define LSEQ  196           // H*W = 14*14
#define HID   768
#define NHEAD 24
#define HDIM  32
#define FFN   3072
#define ROWS  (NB * LSEQ)   // 12544
#define RATE  0.2f
#define LN_EPS 1e-5f

typedef unsigned short bf16_t;                              // raw bf16 bits
typedef short s16x8 __attribute__((ext_vector_type(8)));    // 8 bf16 (4 VGPRs)
typedef float f32x4 __attribute__((ext_vector_type(4)));    // MFMA accumulator

// fp32 -> bf16 round-to-nearest-even (bit pattern in ushort)
__device__ __forceinline__ unsigned short f2bf(float f) {
    unsigned u = __float_as_uint(f);
    unsigned r = u + 0x7fffu + ((u >> 16) & 1u);
    return (unsigned short)(r >> 16);
}

// async global->LDS, 16 B per lane, dest = wave-uniform base + lane*16
#define GLOAD_LDS16(g, l)                                                  \
    __builtin_amdgcn_global_load_lds(                                      \
        (const __attribute__((address_space(1))) void*)(g),                \
        (__attribute__((address_space(3))) void*)(l), 16, 0, 0)

// ---------------------------------------------------------------------------
// fp32 -> bf16 convert for all three weight matrices in one launch.
// n4 counts float4 groups: w_out 147456, w1 589824, w2 589824.
// ---------------------------------------------------------------------------
#define WOUT4 (HID * HID / 4)
#define W14   (FFN * HID / 4)
__global__ __launch_bounds__(256) void cvt_w_kernel(
    const float* __restrict__ w_out, const float* __restrict__ w1,
    const float* __restrict__ w2, bf16_t* __restrict__ wob,
    bf16_t* __restrict__ w1b, bf16_t* __restrict__ w2b)
{
    int i = blockIdx.x * 256 + threadIdx.x;
    const float* src; bf16_t* dst; int off;
    if (i < WOUT4)            { src = w_out; dst = wob; off = i; }
    else if (i < WOUT4 + W14) { src = w1;    dst = w1b; off = i - WOUT4; }
    else                      { src = w2;    dst = w2b; off = i - WOUT4 - W14; }
    float4 v = ((const float4*)src)[off];
    uint2 p;
    p.x = (unsigned)f2bf(v.x) | ((unsigned)f2bf(v.y) << 16);
    p.y = (unsigned)f2bf(v.z) | ((unsigned)f2bf(v.w) << 16);
    ((uint2*)dst)[off] = p;
}

// ---------------------------------------------------------------------------
// LayerNorm over last dim (768). One block (256 threads) per row. bf16 out.
// (Used for LN2 only; LN1 is fused into ln_qkv_kernel.)
// ---------------------------------------------------------------------------
__global__ __launch_bounds__(256) void ln_kernel(
    const float* __restrict__ x, const float* __restrict__ g,
    const float* __restrict__ b, bf16_t* __restrict__ yv)
{
    int row = blockIdx.x;
    int tid = threadIdx.x;  // 0..255
    const float* xr = x + (size_t)row * HID;
    float v0 = xr[tid], v1 = xr[tid + 256], v2 = xr[tid + 512];
    __shared__ float rs[256], rs2[256];
    rs[tid]  = v0 + v1 + v2;
    rs2[tid] = v0 * v0 + v1 * v1 + v2 * v2;
    __syncthreads();
    for (int off = 128; off > 0; off >>= 1) {
        if (tid < off) { rs[tid] += rs[tid + off]; rs2[tid] += rs2[tid + off]; }
        __syncthreads();
    }
    float mean = rs[0] * (1.0f / HID);
    float var  = rs2[0] * (1.0f / HID) - mean * mean;
    float rstd = rsqrtf(var + LN_EPS);
    bf16_t* yr = yv + (size_t)row * HID;
    yr[tid]       = f2bf((v0 - mean) * rstd * g[tid]       + b[tid]);
    yr[tid + 256] = f2bf((v1 - mean) * rstd * g[tid + 256] + b[tid + 256]);
    yr[tid + 512] = f2bf((v2 - mean) * rstd * g[tid + 512] + b[tid + 512]);
}

// ---------------------------------------------------------------------------
// Fused LN1 + per-head QKV projection. One block (768 thr = 12 waves) per
// 4 rows. Outputs bf16 q/k/v.
// ---------------------------------------------------------------------------
__global__ __launch_bounds__(768) void ln_qkv_kernel(
    const float* __restrict__ x, const float* __restrict__ g,
    const float* __restrict__ b,
    const float* __restrict__ wq, const float* __restrict__ wk,
    const float* __restrict__ wv,
    bf16_t* __restrict__ q, bf16_t* __restrict__ k, bf16_t* __restrict__ v)
{
    int tid = threadIdx.x;  // 0..767
    int wv_ = tid >> 6, lane = tid & 63;
    __shared__ float wqs[32 * 33], wks[32 * 33], wvs[32 * 33];
    __shared__ float xs[HID];
    __shared__ float reds[12], reds2[12];
    for (int i = tid; i < 1024; i += 768) {
        int e = i >> 5, d = i & 31;
        wqs[e * 33 + d] = wq[i];
        wks[e * 33 + d] = wk[i];
        wvs[e * 33 + d] = wv[i];
    }
    int h = tid >> 5, e = tid & 31;
    float gg = g[tid], bb = b[tid];

    for (int rr = 0; rr < 4; rr++) {
        int row = blockIdx.x * 4 + rr;
        float xv = x[(size_t)row * HID + tid];
        float s = xv, s2 = xv * xv;
#pragma unroll
        for (int d = 32; d > 0; d >>= 1) {
            s  += __shfl_down(s, d);
            s2 += __shfl_down(s2, d);
        }
        __syncthreads();   // reds reuse from prev iter; also covers wqs staging
        if (lane == 0) { reds[wv_] = s; reds2[wv_] = s2; }
        __syncthreads();
        float ts = 0.f, ts2 = 0.f;
#pragma unroll
        for (int i = 0; i < 12; i++) { ts += reds[i]; ts2 += reds2[i]; }
        float mean = ts * (1.0f / HID);
        float var  = ts2 * (1.0f / HID) - mean * mean;
        float rstd = rsqrtf(var + LN_EPS);
        xs[tid] = (xv - mean) * rstd * gg + bb;
        const float* xvp = xs + h * 32;
        float aq = 0.f, ak = 0.f, av = 0.f;
#pragma unroll
        for (int d = 0; d < 32; d++) {
            float xd = xvp[d];
            aq += xd * wqs[e * 33 + d];
            ak += xd * wks[e * 33 + d];
            av += xd * wvs[e * 33 + d];
        }
        size_t o = (size_t)row * HID + tid;
        q[o] = f2bf(aq); k[o] = f2bf(ak); v[o] = f2bf(av);
    }
}

// ---------------------------------------------------------------------------
// MFMA attention: one block (256 thr = 4 waves) per (h, n). Unchanged.
// ---------------------------------------------------------------------------
#define VT_S 232   // V^T row stride (bf16)
#define P_S  40    // P row stride (bf16)

__global__ __launch_bounds__(256) void attn_mfma_kernel(
    const bf16_t* __restrict__ q, const bf16_t* __restrict__ k,
    const bf16_t* __restrict__ v, const float* __restrict__ rel_bias,
    bf16_t* __restrict__ o)
{
    int h = blockIdx.x;   // 0..23
    int n = blockIdx.y;   // 0..63
    int tid = threadIdx.x;
    int w = tid >> 6, lane = tid & 63;
    int lr = lane & 15;
    int lq = lane >> 4;

    __shared__ __align__(16) bf16_t Qs[208 * 32];
    __shared__ __align__(16) bf16_t Ks[224 * 32];
    __shared__ __align__(16) bf16_t Vt[32 * VT_S];
    __shared__ float bsh[28 * 28];
    __shared__ __align__(16) bf16_t Ps[4][16 * P_S];

    size_t base = (size_t)n * LSEQ * HID + (size_t)h * HDIM;

    for (int i = tid; i < 224 * 4; i += 256) {
        int r = i >> 2, c = i & 3;
        uint4 kv = make_uint4(0, 0, 0, 0);
        if (r < 196) kv = *(const uint4*)&k[base + (size_t)r * HID + c * 8];
        *(uint4*)&Ks[r * 32 + c * 8] = kv;
        if (r < 208) {
            uint4 qv = make_uint4(0, 0, 0, 0);
            if (r < 196) qv = *(const uint4*)&q[base + (size_t)r * HID + c * 8];
            *(uint4*)&Qs[r * 32 + c * 8] = qv;
        }
    }
    for (int i = tid; i < 196 * 16; i += 256) {
        int key = i >> 4, d2 = (i & 15) * 2;
        unsigned u = *(const unsigned*)&v[base + (size_t)key * HID + d2];
        Vt[d2 * VT_S + key]       = (bf16_t)(u & 0xffffu);
        Vt[(d2 + 1) * VT_S + key] = (bf16_t)(u >> 16);
    }
    for (int i = tid; i < 32 * 32; i += 256) {
        int d = i >> 5, kp = i & 31;
        if (kp < 28) Vt[d * VT_S + 196 + kp] = 0;
    }
    for (int i = tid; i < 784; i += 256) bsh[i] = rel_bias[i];
    __syncthreads();

    const float inv_sqrt_d = 0.17677669529663687f;
    bf16_t* P = Ps[w];

    for (int qt = w; qt < 13; qt += 4) {
        s16x8 aQ = *(const s16x8*)&Qs[(qt * 16 + lr) * 32 + lq * 8];

        int bb[4]; bool qvalid[4];
#pragma unroll
        for (int r = 0; r < 4; r++) {
            int qr = qt * 16 + lq * 4 + r;
            qvalid[r] = qr < LSEQ;
            int qq = qvalid[r] ? qr : 0;
            int qi = qq / 14, qj = qq - 14 * (qq / 14);
            bb[r] = (qi + 14) * 28 + (qj + 14);
        }

        f32x4 sf[14];
#pragma unroll
        for (int kt = 0; kt < 14; kt++) {
            s16x8 bK = *(const s16x8*)&Ks[(kt * 16 + lr) * 32 + lq * 8];
            f32x4 z = {};
            sf[kt] = __builtin_amdgcn_mfma_f32_16x16x32_bf16(aQ, bK, z, 0, 0, 0);
        }
#pragma unroll
        for (int kt = 0; kt < 14; kt++) {
            int key = kt * 16 + lr;
            bool kv = key < LSEQ;
            int kk2 = kv ? key : 0;
            int ip = kk2 / 14, jp = kk2 - 14 * ip;
            int boff = ip * 28 + jp;
#pragma unroll
            for (int r = 0; r < 4; r++) {
                float val = (sf[kt][r] + bsh[bb[r] - boff]) * inv_sqrt_d;
                sf[kt][r] = kv ? val : -1e30f;
            }
        }
        float mx[4];
#pragma unroll
        for (int r = 0; r < 4; r++) {
            float m = sf[0][r];
#pragma unroll
            for (int kt = 1; kt < 14; kt++) m = fmaxf(m, sf[kt][r]);
            mx[r] = m;
        }
#pragma unroll
        for (int d = 1; d < 16; d <<= 1)
#pragma unroll
            for (int r = 0; r < 4; r++)
                mx[r] = fmaxf(mx[r], __shfl_xor(mx[r], d));
        float sum[4] = {0.f, 0.f, 0.f, 0.f};
#pragma unroll
        for (int kt = 0; kt < 14; kt++)
#pragma unroll
            for (int r = 0; r < 4; r++) {
                float p = __expf(sf[kt][r] - mx[r]);
                sf[kt][r] = p;
                sum[r] += p;
            }
#pragma unroll
        for (int d = 1; d < 16; d <<= 1)
#pragma unroll
            for (int r = 0; r < 4; r++)
                sum[r] += __shfl_xor(sum[r], d);

        f32x4 oacc[2] = {};
#pragma unroll
        for (int kc = 0; kc < 7; kc++) {
#pragma unroll
            for (int r = 0; r < 4; r++) {
                P[(lq * 4 + r) * P_S + lr]      = f2bf(sf[2 * kc][r]);
                P[(lq * 4 + r) * P_S + 16 + lr] = f2bf(sf[2 * kc + 1][r]);
            }
            s16x8 aP = *(const s16x8*)&P[lr * P_S + lq * 8];
#pragma unroll
            for (int dt = 0; dt < 2; dt++) {
                s16x8 bV = *(const s16x8*)&Vt[(dt * 16 + lr) * VT_S + kc * 32 + lq * 8];
                oacc[dt] = __builtin_amdgcn_mfma_f32_16x16x32_bf16(aP, bV, oacc[dt], 0, 0, 0);
            }
        }
#pragma unroll
        for (int r = 0; r < 4; r++) {
            if (qvalid[r]) {
                float inv_l = 1.0f / sum[r];
                size_t ob = base + (size_t)(qt * 16 + lq * 4 + r) * HID;
                o[ob + lr]      = f2bf(oacc[0][r] * inv_l);
                o[ob + 16 + lr] = f2bf(oacc[1][r] * inv_l);
            }
        }
    }
}

// ---------------------------------------------------------------------------
// bf16 MFMA GEMM v3: C[m,n] = sum_k A[m,k]*B[n,k]. TM x 128 tile (TM=128 or
// 64), BK=64, 256 threads = 4 waves. TM=128: wave quadrant 64x64 (4x4 MFMA
// tiles); TM=64: wave quadrant 32x64 (2x4) — more blocks for N-narrow GEMMs
// (grid occupancy, not resources, limits the N=768 GEMMs).
// XOR-swizzled LDS (conflict-free, verified r6: conflicts 7.2e6 -> 0).
// 1D grid, XCD-aware swizzle (same-m blocks 8 apart -> same XCD L2).
// Epilogue: 1: C=(res+acc)*scale  2: C=gelu(acc+bias)  3: C=(res+acc+bias)*scale
// M mult of TM; N mult of 128; K mult of 64.
// ---------------------------------------------------------------------------
__device__ __forceinline__ float gelu_exact(float x) {
    return 0.5f * x * (1.0f + erff(x * 0.70710678118654752f));
}

template <int MODE, bool OBF, int TM>
__global__ __launch_bounds__(256) void gemm_mfma(
    const bf16_t* __restrict__ A, const bf16_t* __restrict__ B,
    void* __restrict__ Cv, int M, int N, int K,
    const float* __restrict__ bias, const float* __restrict__ res, float scale)
{
    constexpr int MT = TM / 32;       // m-tiles per wave (4 or 2)
    __shared__ __align__(16) bf16_t As[TM * 64];
    __shared__ __align__(16) bf16_t Bs[128 * 64];

    int tid = threadIdx.x;
    // XCD-aware block swizzle: linear id -> (m,n) with same-m blocks 8 apart
    int mb = M / TM, nb = N >> 7;
    int gblk = blockIdx.x;
    int full = mb & ~7;
    int gfull = full * nb;
    int m_, n_;
    if (gblk < gfull) {
        int sg = gblk / (8 * nb), u = gblk - sg * (8 * nb);
        m_ = sg * 8 + (u & 7); n_ = u >> 3;
    } else {
        int u = gblk - gfull, rem = mb - full;
        m_ = full + u % rem; n_ = u / rem;
    }
    int bm = m_ * TM, bn = n_ << 7;

    int w    = tid >> 6;              // wave 0..3
    int lane = tid & 63;
    int wm = (w & 1) * (TM / 2);
    int wn = (w >> 1) * 64;
    int lr = lane & 15;               // m (A) / n (B) / col (C)
    int lq = lane >> 4;               // k-group (A/B) / row-group (C)

    // staging: instr covers 8 rows x 128 B; lane -> row lane>>3,
    // physical chunk lane&7 holds logical chunk (lane&7)^(lane>>3)
    int srowl = lane >> 3;                    // 0..7
    int scb   = ((lane & 7) ^ srowl) * 16;    // swizzled source byte offset
    const char* Ab = (const char*)A;
    const char* Bb = (const char*)B;

    f32x4 acc[MT][4] = {};

    for (int k0 = 0; k0 < K; k0 += 64) {
#pragma unroll
        for (int j = 0; j < TM / 32; j++) {   // A: TM rows
            int rb = w * (TM / 4) + j * 8;
            GLOAD_LDS16(Ab + ((size_t)(bm + rb + srowl) * K + k0) * 2 + scb, &As[rb * 64]);
        }
#pragma unroll
        for (int j = 0; j < 4; j++) {         // B: 128 rows
            int rb = w * 32 + j * 8;
            GLOAD_LDS16(Bb + ((size_t)(bn + rb + srowl) * K + k0) * 2 + scb, &Bs[rb * 64]);
        }
        __syncthreads();

        int sw = lr & 7;
#pragma unroll
        for (int kc = 0; kc < 2; kc++) {
            int cof = (((kc << 2) | lq) ^ sw) * 8;
            s16x8 af[MT], bf[4];
#pragma unroll
            for (int t = 0; t < MT; t++)
                af[t] = *(const s16x8*)&As[(wm + t * 16 + lr) * 64 + cof];
#pragma unroll
            for (int t = 0; t < 4; t++)
                bf[t] = *(const s16x8*)&Bs[(wn + t * 16 + lr) * 64 + cof];
#pragma unroll
            for (int tm = 0; tm < MT; tm++)
#pragma unroll
                for (int tn = 0; tn < 4; tn++)
                    acc[tm][tn] = __builtin_amdgcn_mfma_f32_16x16x32_bf16(
                        af[tm], bf[tn], acc[tm][tn], 0, 0, 0);
        }
        __syncthreads();
    }

#pragma unroll
    for (int tm = 0; tm < MT; tm++) {
#pragma unroll
        for (int tn = 0; tn < 4; tn++) {
#pragma unroll
            for (int r = 0; r < 4; r++) {
                int mrow = bm + wm + tm * 16 + lq * 4 + r;
                int ncol = bn + wn + tn * 16 + lr;
                float vacc = acc[tm][tn][r];
                if (MODE == 1) {
                    vacc = (res[(size_t)mrow * N + ncol] + vacc) * scale;
                } else if (MODE == 2) {
                    vacc = gelu_exact(vacc + bias[ncol]);
                } else if (MODE == 3) {
                    vacc = (res[(size_t)mrow * N + ncol] + vacc + bias[ncol]) * scale;
                }
                if (OBF) ((bf16_t*)Cv)[(size_t)mrow * N + ncol] = f2bf(vacc);
                else     ((float*)Cv)[(size_t)mrow * N + ncol] = vacc;
            }
        }
    }
}

// ---------------------------------------------------------------------------
// Launch
// ---------------------------------------------------------------------------
extern "C" void kernel_launch(void* const* d_in, const int* in_sizes, int n_in,
                              void* d_out, int out_size, void* d_ws, size_t ws_size,
                              hipStream_t stream)
{
    const float* x        = (const float*)d_in[0];
    const float* rel_bias = (const float*)d_in[1];
    const float* wq       = (const float*)d_in[2];
    const float* wk       = (const float*)d_in[3];
    const float* wv       = (const float*)d_in[4];
    const float* w_out    = (const float*)d_in[5];
    const float* ln1_g    = (const float*)d_in[6];
    const float* ln1_b    = (const float*)d_in[7];
    const float* ln2_g    = (const float*)d_in[8];
    const float* ln2_b    = (const float*)d_in[9];
    const float* w1       = (const float*)d_in[10];
    const float* b1       = (const float*)d_in[11];
    const float* w2       = (const float*)d_in[12];
    const float* b2       = (const float*)d_in[13];
    float* out = (float*)d_out;
    float* ws  = (float*)d_ws;

    const size_t SZ = (size_t)ROWS * HID;  // 9,633,792 floats
    // Region map (float units):
    //   [0, SZ/2)    o bf16; y2 bf16 [SZ/2, SZ)
    //   [SZ, 1.5SZ)  q bf16 (dies after attn)   } h bf16 [SZ,3SZ) after attn
    //   [2SZ, 2.5SZ) k bf16 (dies after attn)   }
    //   [3SZ, 3.5SZ) v bf16 (dies after attn)
    //   [4SZ, ...)   bf16 weights: wob 768x768, w1b 3072x768, w2b 768x3072
    bf16_t* q_bf = (bf16_t*)(ws + SZ);
    bf16_t* k_bf = (bf16_t*)(ws + 2 * SZ);
    bf16_t* v_bf = (bf16_t*)(ws + 3 * SZ);
    bf16_t* o_bf = (bf16_t*)ws;
    bf16_t* y2b  = (bf16_t*)(ws + SZ / 2);
    bf16_t* h    = (bf16_t*)(ws + SZ);
    bf16_t* wob  = (bf16_t*)(ws + 4 * SZ);
    bf16_t* w1b  = wob + (size_t)HID * HID;
    bf16_t* w2b  = w1b + (size_t)FFN * HID;

    // 0. weight conversions (one launch)
    cvt_w_kernel<<<(WOUT4 + 2 * W14 + 255) / 256, 256, 0, stream>>>(
        w_out, w1, w2, wob, w1b, w2b);

    // 1+2. fused LN1 + q,k,v per-head projections (bf16 out)
    ln_qkv_kernel<<<ROWS / 4, 768, 0, stream>>>(x, ln1_g, ln1_b, wq, wk, wv,
                                                q_bf, k_bf, v_bf);

    // 3. o = softmax((qk^T + bias)/sqrt(d)) @ v   (MFMA, bf16 out)
    attn_mfma_kernel<<<dim3(NHEAD, NB), 256, 0, stream>>>(q_bf, k_bf, v_bf, rel_bias, o_bf);

    // 4. x1 = (x + o @ w_out^T) * RATE   -> d_out (fp32)   [TM=64: 1176 blks]
    gemm_mfma<1, false, 64><<<(ROWS / 64) * (HID / 128), 256, 0, stream>>>(
        o_bf, wob, out, ROWS, HID, HID, nullptr, x, RATE);

    // 5. y2 = LN2(x1)  (bf16)
    ln_kernel<<<ROWS, 256, 0, stream>>>(out, ln2_g, ln2_b, y2b);

    // 6. h = gelu(y2 @ w1^T + b1)  (bf16)   [TM=128: 2352 blks]
    gemm_mfma<2, true, 128><<<(ROWS / 128) * (FFN / 128), 256, 0, stream>>>(
        y2b, w1b, h, ROWS, FFN, HID, b1, nullptr, 1.0f);

    // 7. out = (x1 + h @ w2^T + b2) * RATE  (fp32)   [TM=64: 1176 blks]
    gemm_mfma<3, false, 64><<<(ROWS / 64) * (HID / 128), 256, 0, stream>>>(
        h, w2b, out, ROWS, HID, FFN, b2, out, RATE);
}

// Round 8
// 454.834 us; speedup vs baseline: 10.2607x; 1.1715x over previous
//
#include <hip/hip_runtime.h>
#include <math.h>

// Problem constants
#define NB    64            // batch
#define LSEQ  196           // H*W = 14*14
#define HID   768
#define NHEAD 24
#define HDIM  32
#define FFN   3072
#define ROWS  (NB * LSEQ)   // 12544
#define RATE  0.2f
#define LN_EPS 1e-5f

typedef unsigned short bf16_t;                              // raw bf16 bits
typedef short s16x8 __attribute__((ext_vector_type(8)));    // 8 bf16 (4 VGPRs)
typedef float f32x4 __attribute__((ext_vector_type(4)));    // MFMA accumulator

// fp32 -> bf16 round-to-nearest-even (bit pattern in ushort)
__device__ __forceinline__ unsigned short f2bf(float f) {
    unsigned u = __float_as_uint(f);
    unsigned r = u + 0x7fffu + ((u >> 16) & 1u);
    return (unsigned short)(r >> 16);
}

// async global->LDS, 16 B per lane, dest = wave-uniform base + lane*16
#define GLOAD_LDS16(g, l)                                                  \
    __builtin_amdgcn_global_load_lds(                                      \
        (const __attribute__((address_space(1))) void*)(g),                \
        (__attribute__((address_space(3))) void*)(l), 16, 0, 0)

// ---------------------------------------------------------------------------
// fp32 -> bf16 convert for all three weight matrices in one launch.
// ---------------------------------------------------------------------------
#define WOUT4 (HID * HID / 4)
#define W14   (FFN * HID / 4)
__global__ __launch_bounds__(256) void cvt_w_kernel(
    const float* __restrict__ w_out, const float* __restrict__ w1,
    const float* __restrict__ w2, bf16_t* __restrict__ wob,
    bf16_t* __restrict__ w1b, bf16_t* __restrict__ w2b)
{
    int i = blockIdx.x * 256 + threadIdx.x;
    const float* src; bf16_t* dst; int off;
    if (i < WOUT4)            { src = w_out; dst = wob; off = i; }
    else if (i < WOUT4 + W14) { src = w1;    dst = w1b; off = i - WOUT4; }
    else                      { src = w2;    dst = w2b; off = i - WOUT4 - W14; }
    float4 v = ((const float4*)src)[off];
    uint2 p;
    p.x = (unsigned)f2bf(v.x) | ((unsigned)f2bf(v.y) << 16);
    p.y = (unsigned)f2bf(v.z) | ((unsigned)f2bf(v.w) << 16);
    ((uint2*)dst)[off] = p;
}

// ---------------------------------------------------------------------------
// LayerNorm over last dim (768). One block (256 threads) per row. bf16 out.
// (LN2 only.)
// ---------------------------------------------------------------------------
__global__ __launch_bounds__(256) void ln_kernel(
    const float* __restrict__ x, const float* __restrict__ g,
    const float* __restrict__ b, bf16_t* __restrict__ yv)
{
    int row = blockIdx.x;
    int tid = threadIdx.x;  // 0..255
    const float* xr = x + (size_t)row * HID;
    float v0 = xr[tid], v1 = xr[tid + 256], v2 = xr[tid + 512];
    __shared__ float rs[256], rs2[256];
    rs[tid]  = v0 + v1 + v2;
    rs2[tid] = v0 * v0 + v1 * v1 + v2 * v2;
    __syncthreads();
    for (int off = 128; off > 0; off >>= 1) {
        if (tid < off) { rs[tid] += rs[tid + off]; rs2[tid] += rs2[tid + off]; }
        __syncthreads();
    }
    float mean = rs[0] * (1.0f / HID);
    float var  = rs2[0] * (1.0f / HID) - mean * mean;
    float rstd = rsqrtf(var + LN_EPS);
    bf16_t* yr = yv + (size_t)row * HID;
    yr[tid]       = f2bf((v0 - mean) * rstd * g[tid]       + b[tid]);
    yr[tid + 256] = f2bf((v1 - mean) * rstd * g[tid + 256] + b[tid + 256]);
    yr[tid + 512] = f2bf((v2 - mean) * rstd * g[tid + 512] + b[tid + 512]);
}

// ---------------------------------------------------------------------------
// Fused LN1 + QKV via MFMA. Per-head projection = (ROWS*24) x 32 x 32 GEMM
// with shared 32x32 weights. One block (256 thr = 4 waves) per 16 tokens.
// Wave w owns tokens w*4..w*4+3: LN via wave-shuffle reduction (no barriers),
// normalized bf16 rows -> LDS X' (tile-of-16 A-frag layout); weights staged
// once (bf16 B-frags in VGPRs). Wave then runs its own 6 tiles x 6 MFMAs
// (q,k,v x two 16-col halves). Single __syncthreads (weight staging).
// ---------------------------------------------------------------------------
#define QKV_T 16   // tokens per block
__global__ __launch_bounds__(256) void ln_qkv_mfma_kernel(
    const float* __restrict__ x, const float* __restrict__ g,
    const float* __restrict__ b,
    const float* __restrict__ wq, const float* __restrict__ wk,
    const float* __restrict__ wv,
    bf16_t* __restrict__ q, bf16_t* __restrict__ k, bf16_t* __restrict__ v)
{
    int tid = threadIdx.x;
    int w = tid >> 6, lane = tid & 63;
    int lr = lane & 15, lq = lane >> 4;

    __shared__ __align__(16) bf16_t Xs[QKV_T * 24 * 32];   // 24576 B
    __shared__ __align__(16) bf16_t Wqs[32 * 32];          //  2048 B x3
    __shared__ __align__(16) bf16_t Wks[32 * 32];
    __shared__ __align__(16) bf16_t Wvs[32 * 32];

    // stage weights fp32 -> bf16
    for (int i = tid; i < 1024; i += 256) {
        Wqs[i] = f2bf(wq[i]);
        Wks[i] = f2bf(wk[i]);
        Wvs[i] = f2bf(wv[i]);
    }

    // gamma/beta for this lane's elements (hoisted; same for all 4 tokens)
    float4 gv[3], bv[3];
#pragma unroll
    for (int i = 0; i < 3; i++) {
        gv[i] = ((const float4*)g)[lane + i * 64];
        bv[i] = ((const float4*)b)[lane + i * 64];
    }

    // LN phase: wave w handles tokens w*4..w*4+3 (no cross-wave deps)
    for (int j = 0; j < 4; j++) {
        int lt = w * 4 + j;
        size_t row = (size_t)blockIdx.x * QKV_T + lt;
        const float4* xr = (const float4*)(x + row * HID);
        float4 xv[3];
        float s = 0.f, s2 = 0.f;
#pragma unroll
        for (int i = 0; i < 3; i++) {
            xv[i] = xr[lane + i * 64];
            s  += xv[i].x + xv[i].y + xv[i].z + xv[i].w;
            s2 += xv[i].x * xv[i].x + xv[i].y * xv[i].y
                + xv[i].z * xv[i].z + xv[i].w * xv[i].w;
        }
#pragma unroll
        for (int d = 1; d < 64; d <<= 1) {
            s  += __shfl_xor(s, d);
            s2 += __shfl_xor(s2, d);
        }
        float mean = s * (1.0f / HID);
        float rstd = rsqrtf(s2 * (1.0f / HID) - mean * mean + LN_EPS);
#pragma unroll
        for (int i = 0; i < 3; i++) {
            int idx  = (lane + i * 64) * 4;          // element 0..764, 4-aligned
            int head = idx >> 5, d0 = idx & 31;
            float o0 = (xv[i].x - mean) * rstd * gv[i].x + bv[i].x;
            float o1 = (xv[i].y - mean) * rstd * gv[i].y + bv[i].y;
            float o2 = (xv[i].z - mean) * rstd * gv[i].z + bv[i].z;
            float o3 = (xv[i].w - mean) * rstd * gv[i].w + bv[i].w;
            uint2 p;
            p.x = (unsigned)f2bf(o0) | ((unsigned)f2bf(o1) << 16);
            p.y = (unsigned)f2bf(o2) | ((unsigned)f2bf(o3) << 16);
            *(uint2*)&Xs[(lt * 24 + head) * 32 + d0] = p;
        }
    }
    __syncthreads();   // weights staged by all threads

    // preload B-frags: B[n=lr(+16)][k=lq*8..+8]
    s16x8 bq[2], bk[2], bvv[2];
    bq[0]  = *(const s16x8*)&Wqs[lr * 32 + lq * 8];
    bq[1]  = *(const s16x8*)&Wqs[(16 + lr) * 32 + lq * 8];
    bk[0]  = *(const s16x8*)&Wks[lr * 32 + lq * 8];
    bk[1]  = *(const s16x8*)&Wks[(16 + lr) * 32 + lq * 8];
    bvv[0] = *(const s16x8*)&Wvs[lr * 32 + lq * 8];
    bvv[1] = *(const s16x8*)&Wvs[(16 + lr) * 32 + lq * 8];

    // MFMA phase: wave w owns tiles w*6..w*6+5 (X' rows w*96..w*96+95,
    // i.e. exactly its own 4 tokens x 24 heads)
    for (int t = 0; t < 6; t++) {
        int tile = w * 6 + t;
        s16x8 aX = *(const s16x8*)&Xs[(tile * 16 + lr) * 32 + lq * 8];
        f32x4 z = {};
        f32x4 aq0 = __builtin_amdgcn_mfma_f32_16x16x32_bf16(aX, bq[0],  z, 0, 0, 0);
        f32x4 aq1 = __builtin_amdgcn_mfma_f32_16x16x32_bf16(aX, bq[1],  z, 0, 0, 0);
        f32x4 ak0 = __builtin_amdgcn_mfma_f32_16x16x32_bf16(aX, bk[0],  z, 0, 0, 0);
        f32x4 ak1 = __builtin_amdgcn_mfma_f32_16x16x32_bf16(aX, bk[1],  z, 0, 0, 0);
        f32x4 av0 = __builtin_amdgcn_mfma_f32_16x16x32_bf16(aX, bvv[0], z, 0, 0, 0);
        f32x4 av1 = __builtin_amdgcn_mfma_f32_16x16x32_bf16(aX, bvv[1], z, 0, 0, 0);
        int rbase = tile * 16 + lq * 4;
#pragma unroll
        for (int r = 0; r < 4; r++) {
            int xrow = rbase + r;
            int t_loc = xrow / 24, head = xrow - t_loc * 24;
            size_t gb = ((size_t)blockIdx.x * QKV_T + t_loc) * HID + head * 32;
            q[gb + lr]      = f2bf(aq0[r]);
            q[gb + 16 + lr] = f2bf(aq1[r]);
            k[gb + lr]      = f2bf(ak0[r]);
            k[gb + 16 + lr] = f2bf(ak1[r]);
            v[gb + lr]      = f2bf(av0[r]);
            v[gb + 16 + lr] = f2bf(av1[r]);
        }
    }
}

// ---------------------------------------------------------------------------
// MFMA attention: one block (256 thr = 4 waves) per (h, n). Unchanged.
// ---------------------------------------------------------------------------
#define VT_S 232   // V^T row stride (bf16)
#define P_S  40    // P row stride (bf16)

__global__ __launch_bounds__(256) void attn_mfma_kernel(
    const bf16_t* __restrict__ q, const bf16_t* __restrict__ k,
    const bf16_t* __restrict__ v, const float* __restrict__ rel_bias,
    bf16_t* __restrict__ o)
{
    int h = blockIdx.x;   // 0..23
    int n = blockIdx.y;   // 0..63
    int tid = threadIdx.x;
    int w = tid >> 6, lane = tid & 63;
    int lr = lane & 15;
    int lq = lane >> 4;

    __shared__ __align__(16) bf16_t Qs[208 * 32];
    __shared__ __align__(16) bf16_t Ks[224 * 32];
    __shared__ __align__(16) bf16_t Vt[32 * VT_S];
    __shared__ float bsh[28 * 28];
    __shared__ __align__(16) bf16_t Ps[4][16 * P_S];

    size_t base = (size_t)n * LSEQ * HID + (size_t)h * HDIM;

    for (int i = tid; i < 224 * 4; i += 256) {
        int r = i >> 2, c = i & 3;
        uint4 kv = make_uint4(0, 0, 0, 0);
        if (r < 196) kv = *(const uint4*)&k[base + (size_t)r * HID + c * 8];
        *(uint4*)&Ks[r * 32 + c * 8] = kv;
        if (r < 208) {
            uint4 qv = make_uint4(0, 0, 0, 0);
            if (r < 196) qv = *(const uint4*)&q[base + (size_t)r * HID + c * 8];
            *(uint4*)&Qs[r * 32 + c * 8] = qv;
        }
    }
    for (int i = tid; i < 196 * 16; i += 256) {
        int key = i >> 4, d2 = (i & 15) * 2;
        unsigned u = *(const unsigned*)&v[base + (size_t)key * HID + d2];
        Vt[d2 * VT_S + key]       = (bf16_t)(u & 0xffffu);
        Vt[(d2 + 1) * VT_S + key] = (bf16_t)(u >> 16);
    }
    for (int i = tid; i < 32 * 32; i += 256) {
        int d = i >> 5, kp = i & 31;
        if (kp < 28) Vt[d * VT_S + 196 + kp] = 0;
    }
    for (int i = tid; i < 784; i += 256) bsh[i] = rel_bias[i];
    __syncthreads();

    const float inv_sqrt_d = 0.17677669529663687f;
    bf16_t* P = Ps[w];

    for (int qt = w; qt < 13; qt += 4) {
        s16x8 aQ = *(const s16x8*)&Qs[(qt * 16 + lr) * 32 + lq * 8];

        int bb[4]; bool qvalid[4];
#pragma unroll
        for (int r = 0; r < 4; r++) {
            int qr = qt * 16 + lq * 4 + r;
            qvalid[r] = qr < LSEQ;
            int qq = qvalid[r] ? qr : 0;
            int qi = qq / 14, qj = qq - 14 * (qq / 14);
            bb[r] = (qi + 14) * 28 + (qj + 14);
        }

        f32x4 sf[14];
#pragma unroll
        for (int kt = 0; kt < 14; kt++) {
            s16x8 bK = *(const s16x8*)&Ks[(kt * 16 + lr) * 32 + lq * 8];
            f32x4 z = {};
            sf[kt] = __builtin_amdgcn_mfma_f32_16x16x32_bf16(aQ, bK, z, 0, 0, 0);
        }
#pragma unroll
        for (int kt = 0; kt < 14; kt++) {
            int key = kt * 16 + lr;
            bool kv = key < LSEQ;
            int kk2 = kv ? key : 0;
            int ip = kk2 / 14, jp = kk2 - 14 * ip;
            int boff = ip * 28 + jp;
#pragma unroll
            for (int r = 0; r < 4; r++) {
                float val = (sf[kt][r] + bsh[bb[r] - boff]) * inv_sqrt_d;
                sf[kt][r] = kv ? val : -1e30f;
            }
        }
        float mx[4];
#pragma unroll
        for (int r = 0; r < 4; r++) {
            float m = sf[0][r];
#pragma unroll
            for (int kt = 1; kt < 14; kt++) m = fmaxf(m, sf[kt][r]);
            mx[r] = m;
        }
#pragma unroll
        for (int d = 1; d < 16; d <<= 1)
#pragma unroll
            for (int r = 0; r < 4; r++)
                mx[r] = fmaxf(mx[r], __shfl_xor(mx[r], d));
        float sum[4] = {0.f, 0.f, 0.f, 0.f};
#pragma unroll
        for (int kt = 0; kt < 14; kt++)
#pragma unroll
            for (int r = 0; r < 4; r++) {
                float p = __expf(sf[kt][r] - mx[r]);
                sf[kt][r] = p;
                sum[r] += p;
            }
#pragma unroll
        for (int d = 1; d < 16; d <<= 1)
#pragma unroll
            for (int r = 0; r < 4; r++)
                sum[r] += __shfl_xor(sum[r], d);

        f32x4 oacc[2] = {};
#pragma unroll
        for (int kc = 0; kc < 7; kc++) {
#pragma unroll
            for (int r = 0; r < 4; r++) {
                P[(lq * 4 + r) * P_S + lr]      = f2bf(sf[2 * kc][r]);
                P[(lq * 4 + r) * P_S + 16 + lr] = f2bf(sf[2 * kc + 1][r]);
            }
            s16x8 aP = *(const s16x8*)&P[lr * P_S + lq * 8];
#pragma unroll
            for (int dt = 0; dt < 2; dt++) {
                s16x8 bV = *(const s16x8*)&Vt[(dt * 16 + lr) * VT_S + kc * 32 + lq * 8];
                oacc[dt] = __builtin_amdgcn_mfma_f32_16x16x32_bf16(aP, bV, oacc[dt], 0, 0, 0);
            }
        }
#pragma unroll
        for (int r = 0; r < 4; r++) {
            if (qvalid[r]) {
                float inv_l = 1.0f / sum[r];
                size_t ob = base + (size_t)(qt * 16 + lq * 4 + r) * HID;
                o[ob + lr]      = f2bf(oacc[0][r] * inv_l);
                o[ob + 16 + lr] = f2bf(oacc[1][r] * inv_l);
            }
        }
    }
}

// ---------------------------------------------------------------------------
// bf16 MFMA GEMM: C[m,n] = sum_k A[m,k]*B[n,k]. TM x 128 tile, BK=64,
// 256 threads = 4 waves. XOR-swizzled LDS (conflict-free, r6-verified).
// 1D grid, XCD-aware swizzle. Epilogue modes 1/2/3 as before.
// ---------------------------------------------------------------------------
__device__ __forceinline__ float gelu_exact(float x) {
    return 0.5f * x * (1.0f + erff(x * 0.70710678118654752f));
}

template <int MODE, bool OBF, int TM>
__global__ __launch_bounds__(256) void gemm_mfma(
    const bf16_t* __restrict__ A, const bf16_t* __restrict__ B,
    void* __restrict__ Cv, int M, int N, int K,
    const float* __restrict__ bias, const float* __restrict__ res, float scale)
{
    constexpr int MT = TM / 32;       // m-tiles per wave (4 or 2)
    __shared__ __align__(16) bf16_t As[TM * 64];
    __shared__ __align__(16) bf16_t Bs[128 * 64];

    int tid = threadIdx.x;
    int mb = M / TM, nb = N >> 7;
    int gblk = blockIdx.x;
    int full = mb & ~7;
    int gfull = full * nb;
    int m_, n_;
    if (gblk < gfull) {
        int sg = gblk / (8 * nb), u = gblk - sg * (8 * nb);
        m_ = sg * 8 + (u & 7); n_ = u >> 3;
    } else {
        int u = gblk - gfull, rem = mb - full;
        m_ = full + u % rem; n_ = u / rem;
    }
    int bm = m_ * TM, bn = n_ << 7;

    int w    = tid >> 6;
    int lane = tid & 63;
    int wm = (w & 1) * (TM / 2);
    int wn = (w >> 1) * 64;
    int lr = lane & 15;
    int lq = lane >> 4;

    int srowl = lane >> 3;                    // 0..7
    int scb   = ((lane & 7) ^ srowl) * 16;    // swizzled source byte offset
    const char* Ab = (const char*)A;
    const char* Bb = (const char*)B;

    f32x4 acc[MT][4] = {};

    for (int k0 = 0; k0 < K; k0 += 64) {
#pragma unroll
        for (int j = 0; j < TM / 32; j++) {
            int rb = w * (TM / 4) + j * 8;
            GLOAD_LDS16(Ab + ((size_t)(bm + rb + srowl) * K + k0) * 2 + scb, &As[rb * 64]);
        }
#pragma unroll
        for (int j = 0; j < 4; j++) {
            int rb = w * 32 + j * 8;
            GLOAD_LDS16(Bb + ((size_t)(bn + rb + srowl) * K + k0) * 2 + scb, &Bs[rb * 64]);
        }
        __syncthreads();

        int sw = lr & 7;
#pragma unroll
        for (int kc = 0; kc < 2; kc++) {
            int cof = (((kc << 2) | lq) ^ sw) * 8;
            s16x8 af[MT], bf[4];
#pragma unroll
            for (int t = 0; t < MT; t++)
                af[t] = *(const s16x8*)&As[(wm + t * 16 + lr) * 64 + cof];
#pragma unroll
            for (int t = 0; t < 4; t++)
                bf[t] = *(const s16x8*)&Bs[(wn + t * 16 + lr) * 64 + cof];
#pragma unroll
            for (int tm = 0; tm < MT; tm++)
#pragma unroll
                for (int tn = 0; tn < 4; tn++)
                    acc[tm][tn] = __builtin_amdgcn_mfma_f32_16x16x32_bf16(
                        af[tm], bf[tn], acc[tm][tn], 0, 0, 0);
        }
        __syncthreads();
    }

#pragma unroll
    for (int tm = 0; tm < MT; tm++) {
#pragma unroll
        for (int tn = 0; tn < 4; tn++) {
#pragma unroll
            for (int r = 0; r < 4; r++) {
                int mrow = bm + wm + tm * 16 + lq * 4 + r;
                int ncol = bn + wn + tn * 16 + lr;
                float vacc = acc[tm][tn][r];
                if (MODE == 1) {
                    vacc = (res[(size_t)mrow * N + ncol] + vacc) * scale;
                } else if (MODE == 2) {
                    vacc = gelu_exact(vacc + bias[ncol]);
                } else if (MODE == 3) {
                    vacc = (res[(size_t)mrow * N + ncol] + vacc + bias[ncol]) * scale;
                }
                if (OBF) ((bf16_t*)Cv)[(size_t)mrow * N + ncol] = f2bf(vacc);
                else     ((float*)Cv)[(size_t)mrow * N + ncol] = vacc;
            }
        }
    }
}

// ---------------------------------------------------------------------------
// Launch
// ---------------------------------------------------------------------------
extern "C" void kernel_launch(void* const* d_in, const int* in_sizes, int n_in,
                              void* d_out, int out_size, void* d_ws, size_t ws_size,
                              hipStream_t stream)
{
    const float* x        = (const float*)d_in[0];
    const float* rel_bias = (const float*)d_in[1];
    const float* wq       = (const float*)d_in[2];
    const float* wk       = (const float*)d_in[3];
    const float* wv       = (const float*)d_in[4];
    const float* w_out    = (const float*)d_in[5];
    const float* ln1_g    = (const float*)d_in[6];
    const float* ln1_b    = (const float*)d_in[7];
    const float* ln2_g    = (const float*)d_in[8];
    const float* ln2_b    = (const float*)d_in[9];
    const float* w1       = (const float*)d_in[10];
    const float* b1       = (const float*)d_in[11];
    const float* w2       = (const float*)d_in[12];
    const float* b2       = (const float*)d_in[13];
    float* out = (float*)d_out;
    float* ws  = (float*)d_ws;

    const size_t SZ = (size_t)ROWS * HID;  // 9,633,792 floats
    // Region map (float units):
    //   [0, SZ/2)    o bf16; y2 bf16 [SZ/2, SZ)
    //   [SZ, 1.5SZ)  q bf16 (dies after attn)   } h bf16 [SZ,3SZ) after attn
    //   [2SZ, 2.5SZ) k bf16 (dies after attn)   }
    //   [3SZ, 3.5SZ) v bf16 (dies after attn)
    //   [4SZ, ...)   bf16 weights: wob 768x768, w1b 3072x768, w2b 768x3072
    bf16_t* q_bf = (bf16_t*)(ws + SZ);
    bf16_t* k_bf = (bf16_t*)(ws + 2 * SZ);
    bf16_t* v_bf = (bf16_t*)(ws + 3 * SZ);
    bf16_t* o_bf = (bf16_t*)ws;
    bf16_t* y2b  = (bf16_t*)(ws + SZ / 2);
    bf16_t* h    = (bf16_t*)(ws + SZ);
    bf16_t* wob  = (bf16_t*)(ws + 4 * SZ);
    bf16_t* w1b  = wob + (size_t)HID * HID;
    bf16_t* w2b  = w1b + (size_t)FFN * HID;

    // 0. weight conversions (one launch)
    cvt_w_kernel<<<(WOUT4 + 2 * W14 + 255) / 256, 256, 0, stream>>>(
        w_out, w1, w2, wob, w1b, w2b);

    // 1+2. fused LN1 + q,k,v per-head projections (MFMA, bf16 out)
    ln_qkv_mfma_kernel<<<ROWS / QKV_T, 256, 0, stream>>>(
        x, ln1_g, ln1_b, wq, wk, wv, q_bf, k_bf, v_bf);

    // 3. o = softmax((qk^T + bias)/sqrt(d)) @ v   (MFMA, bf16 out)
    attn_mfma_kernel<<<dim3(NHEAD, NB), 256, 0, stream>>>(q_bf, k_bf, v_bf, rel_bias, o_bf);

    // 4. x1 = (x + o @ w_out^T) * RATE   -> d_out (fp32)   [TM=64: 1176 blks]
    gemm_mfma<1, false, 64><<<(ROWS / 64) * (HID / 128), 256, 0, stream>>>(
        o_bf, wob, out, ROWS, HID, HID, nullptr, x, RATE);

    // 5. y2 = LN2(x1)  (bf16)
    ln_kernel<<<ROWS, 256, 0, stream>>>(out, ln2_g, ln2_b, y2b);

    // 6. h = gelu(y2 @ w1^T + b1)  (bf16)   [TM=128: 2352 blks]
    gemm_mfma<2, true, 128><<<(ROWS / 128) * (FFN / 128), 256, 0, stream>>>(
        y2b, w1b, h, ROWS, FFN, HID, b1, nullptr, 1.0f);

    // 7. out = (x1 + h @ w2^T + b2) * RATE  (fp32)   [TM=64: 1176 blks]
    gemm_mfma<3, false, 64><<<(ROWS / 64) * (HID / 128), 256, 0, stream>>>(
        h, w2b, out, ROWS, HID, FFN, b2, out, RATE);
}

// Round 9
// 453.821 us; speedup vs baseline: 10.2836x; 1.0022x over previous
//
#include <hip/hip_runtime.h>
#include <math.h>

// Problem constants
#define NB    64            // batch
#define LSEQ  196           // H*W = 14*14
#define HID   768
#define NHEAD 24
#define HDIM  32
#define FFN   3072
#define ROWS  (NB * LSEQ)   // 12544
#define RATE  0.2f
#define LN_EPS 1e-5f

typedef unsigned short bf16_t;                              // raw bf16 bits
typedef short s16x8 __attribute__((ext_vector_type(8)));    // 8 bf16 (4 VGPRs)
typedef float f32x4 __attribute__((ext_vector_type(4)));    // MFMA accumulator

// fp32 -> bf16 round-to-nearest-even (bit pattern in ushort)
__device__ __forceinline__ unsigned short f2bf(float f) {
    unsigned u = __float_as_uint(f);
    unsigned r = u + 0x7fffu + ((u >> 16) & 1u);
    return (unsigned short)(r >> 16);
}

// async global->LDS, 16 B per lane, dest = wave-uniform base + lane*16
#define GLOAD_LDS16(g, l)                                                  \
    __builtin_amdgcn_global_load_lds(                                      \
        (const __attribute__((address_space(1))) void*)(g),                \
        (__attribute__((address_space(3))) void*)(l), 16, 0, 0)

// ---------------------------------------------------------------------------
// fp32 -> bf16 convert for all three weight matrices in one launch.
// ---------------------------------------------------------------------------
#define WOUT4 (HID * HID / 4)
#define W14   (FFN * HID / 4)
__global__ __launch_bounds__(256) void cvt_w_kernel(
    const float* __restrict__ w_out, const float* __restrict__ w1,
    const float* __restrict__ w2, bf16_t* __restrict__ wob,
    bf16_t* __restrict__ w1b, bf16_t* __restrict__ w2b)
{
    int i = blockIdx.x * 256 + threadIdx.x;
    const float* src; bf16_t* dst; int off;
    if (i < WOUT4)            { src = w_out; dst = wob; off = i; }
    else if (i < WOUT4 + W14) { src = w1;    dst = w1b; off = i - WOUT4; }
    else                      { src = w2;    dst = w2b; off = i - WOUT4 - W14; }
    float4 v = ((const float4*)src)[off];
    uint2 p;
    p.x = (unsigned)f2bf(v.x) | ((unsigned)f2bf(v.y) << 16);
    p.y = (unsigned)f2bf(v.z) | ((unsigned)f2bf(v.w) << 16);
    ((uint2*)dst)[off] = p;
}

// ---------------------------------------------------------------------------
// LayerNorm over last dim (768). One block (256 threads) per row. bf16 out.
// (LN2 only.)
// ---------------------------------------------------------------------------
__global__ __launch_bounds__(256) void ln_kernel(
    const float* __restrict__ x, const float* __restrict__ g,
    const float* __restrict__ b, bf16_t* __restrict__ yv)
{
    int row = blockIdx.x;
    int tid = threadIdx.x;  // 0..255
    const float* xr = x + (size_t)row * HID;
    float v0 = xr[tid], v1 = xr[tid + 256], v2 = xr[tid + 512];
    __shared__ float rs[256], rs2[256];
    rs[tid]  = v0 + v1 + v2;
    rs2[tid] = v0 * v0 + v1 * v1 + v2 * v2;
    __syncthreads();
    for (int off = 128; off > 0; off >>= 1) {
        if (tid < off) { rs[tid] += rs[tid + off]; rs2[tid] += rs2[tid + off]; }
        __syncthreads();
    }
    float mean = rs[0] * (1.0f / HID);
    float var  = rs2[0] * (1.0f / HID) - mean * mean;
    float rstd = rsqrtf(var + LN_EPS);
    bf16_t* yr = yv + (size_t)row * HID;
    yr[tid]       = f2bf((v0 - mean) * rstd * g[tid]       + b[tid]);
    yr[tid + 256] = f2bf((v1 - mean) * rstd * g[tid + 256] + b[tid + 256]);
    yr[tid + 512] = f2bf((v2 - mean) * rstd * g[tid + 512] + b[tid + 512]);
}

// ---------------------------------------------------------------------------
// Fused LN1 + QKV via MFMA. One block (256 thr = 4 waves) per 16 tokens.
// (r8-verified; off the hot list.)
// ---------------------------------------------------------------------------
#define QKV_T 16   // tokens per block
__global__ __launch_bounds__(256) void ln_qkv_mfma_kernel(
    const float* __restrict__ x, const float* __restrict__ g,
    const float* __restrict__ b,
    const float* __restrict__ wq, const float* __restrict__ wk,
    const float* __restrict__ wv,
    bf16_t* __restrict__ q, bf16_t* __restrict__ k, bf16_t* __restrict__ v)
{
    int tid = threadIdx.x;
    int w = tid >> 6, lane = tid & 63;
    int lr = lane & 15, lq = lane >> 4;

    __shared__ __align__(16) bf16_t Xs[QKV_T * 24 * 32];   // 24576 B
    __shared__ __align__(16) bf16_t Wqs[32 * 32];          //  2048 B x3
    __shared__ __align__(16) bf16_t Wks[32 * 32];
    __shared__ __align__(16) bf16_t Wvs[32 * 32];

    for (int i = tid; i < 1024; i += 256) {
        Wqs[i] = f2bf(wq[i]);
        Wks[i] = f2bf(wk[i]);
        Wvs[i] = f2bf(wv[i]);
    }

    float4 gv[3], bv[3];
#pragma unroll
    for (int i = 0; i < 3; i++) {
        gv[i] = ((const float4*)g)[lane + i * 64];
        bv[i] = ((const float4*)b)[lane + i * 64];
    }

    for (int j = 0; j < 4; j++) {
        int lt = w * 4 + j;
        size_t row = (size_t)blockIdx.x * QKV_T + lt;
        const float4* xr = (const float4*)(x + row * HID);
        float4 xv[3];
        float s = 0.f, s2 = 0.f;
#pragma unroll
        for (int i = 0; i < 3; i++) {
            xv[i] = xr[lane + i * 64];
            s  += xv[i].x + xv[i].y + xv[i].z + xv[i].w;
            s2 += xv[i].x * xv[i].x + xv[i].y * xv[i].y
                + xv[i].z * xv[i].z + xv[i].w * xv[i].w;
        }
#pragma unroll
        for (int d = 1; d < 64; d <<= 1) {
            s  += __shfl_xor(s, d);
            s2 += __shfl_xor(s2, d);
        }
        float mean = s * (1.0f / HID);
        float rstd = rsqrtf(s2 * (1.0f / HID) - mean * mean + LN_EPS);
#pragma unroll
        for (int i = 0; i < 3; i++) {
            int idx  = (lane + i * 64) * 4;
            int head = idx >> 5, d0 = idx & 31;
            float o0 = (xv[i].x - mean) * rstd * gv[i].x + bv[i].x;
            float o1 = (xv[i].y - mean) * rstd * gv[i].y + bv[i].y;
            float o2 = (xv[i].z - mean) * rstd * gv[i].z + bv[i].z;
            float o3 = (xv[i].w - mean) * rstd * gv[i].w + bv[i].w;
            uint2 p;
            p.x = (unsigned)f2bf(o0) | ((unsigned)f2bf(o1) << 16);
            p.y = (unsigned)f2bf(o2) | ((unsigned)f2bf(o3) << 16);
            *(uint2*)&Xs[(lt * 24 + head) * 32 + d0] = p;
        }
    }
    __syncthreads();

    s16x8 bq[2], bk[2], bvv[2];
    bq[0]  = *(const s16x8*)&Wqs[lr * 32 + lq * 8];
    bq[1]  = *(const s16x8*)&Wqs[(16 + lr) * 32 + lq * 8];
    bk[0]  = *(const s16x8*)&Wks[lr * 32 + lq * 8];
    bk[1]  = *(const s16x8*)&Wks[(16 + lr) * 32 + lq * 8];
    bvv[0] = *(const s16x8*)&Wvs[lr * 32 + lq * 8];
    bvv[1] = *(const s16x8*)&Wvs[(16 + lr) * 32 + lq * 8];

    for (int t = 0; t < 6; t++) {
        int tile = w * 6 + t;
        s16x8 aX = *(const s16x8*)&Xs[(tile * 16 + lr) * 32 + lq * 8];
        f32x4 z = {};
        f32x4 aq0 = __builtin_amdgcn_mfma_f32_16x16x32_bf16(aX, bq[0],  z, 0, 0, 0);
        f32x4 aq1 = __builtin_amdgcn_mfma_f32_16x16x32_bf16(aX, bq[1],  z, 0, 0, 0);
        f32x4 ak0 = __builtin_amdgcn_mfma_f32_16x16x32_bf16(aX, bk[0],  z, 0, 0, 0);
        f32x4 ak1 = __builtin_amdgcn_mfma_f32_16x16x32_bf16(aX, bk[1],  z, 0, 0, 0);
        f32x4 av0 = __builtin_amdgcn_mfma_f32_16x16x32_bf16(aX, bvv[0], z, 0, 0, 0);
        f32x4 av1 = __builtin_amdgcn_mfma_f32_16x16x32_bf16(aX, bvv[1], z, 0, 0, 0);
        int rbase = tile * 16 + lq * 4;
#pragma unroll
        for (int r = 0; r < 4; r++) {
            int xrow = rbase + r;
            int t_loc = xrow / 24, head = xrow - t_loc * 24;
            size_t gb = ((size_t)blockIdx.x * QKV_T + t_loc) * HID + head * 32;
            q[gb + lr]      = f2bf(aq0[r]);
            q[gb + 16 + lr] = f2bf(aq1[r]);
            k[gb + lr]      = f2bf(ak0[r]);
            k[gb + 16 + lr] = f2bf(ak1[r]);
            v[gb + lr]      = f2bf(av0[r]);
            v[gb + 16 + lr] = f2bf(av1[r]);
        }
    }
}

// ---------------------------------------------------------------------------
// MFMA attention: one block (256 thr = 4 waves) per (h, n). Unchanged.
// ---------------------------------------------------------------------------
#define VT_S 232   // V^T row stride (bf16)
#define P_S  40    // P row stride (bf16)

__global__ __launch_bounds__(256) void attn_mfma_kernel(
    const bf16_t* __restrict__ q, const bf16_t* __restrict__ k,
    const bf16_t* __restrict__ v, const float* __restrict__ rel_bias,
    bf16_t* __restrict__ o)
{
    int h = blockIdx.x;   // 0..23
    int n = blockIdx.y;   // 0..63
    int tid = threadIdx.x;
    int w = tid >> 6, lane = tid & 63;
    int lr = lane & 15;
    int lq = lane >> 4;

    __shared__ __align__(16) bf16_t Qs[208 * 32];
    __shared__ __align__(16) bf16_t Ks[224 * 32];
    __shared__ __align__(16) bf16_t Vt[32 * VT_S];
    __shared__ float bsh[28 * 28];
    __shared__ __align__(16) bf16_t Ps[4][16 * P_S];

    size_t base = (size_t)n * LSEQ * HID + (size_t)h * HDIM;

    for (int i = tid; i < 224 * 4; i += 256) {
        int r = i >> 2, c = i & 3;
        uint4 kv = make_uint4(0, 0, 0, 0);
        if (r < 196) kv = *(const uint4*)&k[base + (size_t)r * HID + c * 8];
        *(uint4*)&Ks[r * 32 + c * 8] = kv;
        if (r < 208) {
            uint4 qv = make_uint4(0, 0, 0, 0);
            if (r < 196) qv = *(const uint4*)&q[base + (size_t)r * HID + c * 8];
            *(uint4*)&Qs[r * 32 + c * 8] = qv;
        }
    }
    for (int i = tid; i < 196 * 16; i += 256) {
        int key = i >> 4, d2 = (i & 15) * 2;
        unsigned u = *(const unsigned*)&v[base + (size_t)key * HID + d2];
        Vt[d2 * VT_S + key]       = (bf16_t)(u & 0xffffu);
        Vt[(d2 + 1) * VT_S + key] = (bf16_t)(u >> 16);
    }
    for (int i = tid; i < 32 * 32; i += 256) {
        int d = i >> 5, kp = i & 31;
        if (kp < 28) Vt[d * VT_S + 196 + kp] = 0;
    }
    for (int i = tid; i < 784; i += 256) bsh[i] = rel_bias[i];
    __syncthreads();

    const float inv_sqrt_d = 0.17677669529663687f;
    bf16_t* P = Ps[w];

    for (int qt = w; qt < 13; qt += 4) {
        s16x8 aQ = *(const s16x8*)&Qs[(qt * 16 + lr) * 32 + lq * 8];

        int bb[4]; bool qvalid[4];
#pragma unroll
        for (int r = 0; r < 4; r++) {
            int qr = qt * 16 + lq * 4 + r;
            qvalid[r] = qr < LSEQ;
            int qq = qvalid[r] ? qr : 0;
            int qi = qq / 14, qj = qq - 14 * (qq / 14);
            bb[r] = (qi + 14) * 28 + (qj + 14);
        }

        f32x4 sf[14];
#pragma unroll
        for (int kt = 0; kt < 14; kt++) {
            s16x8 bK = *(const s16x8*)&Ks[(kt * 16 + lr) * 32 + lq * 8];
            f32x4 z = {};
            sf[kt] = __builtin_amdgcn_mfma_f32_16x16x32_bf16(aQ, bK, z, 0, 0, 0);
        }
#pragma unroll
        for (int kt = 0; kt < 14; kt++) {
            int key = kt * 16 + lr;
            bool kv = key < LSEQ;
            int kk2 = kv ? key : 0;
            int ip = kk2 / 14, jp = kk2 - 14 * ip;
            int boff = ip * 28 + jp;
#pragma unroll
            for (int r = 0; r < 4; r++) {
                float val = (sf[kt][r] + bsh[bb[r] - boff]) * inv_sqrt_d;
                sf[kt][r] = kv ? val : -1e30f;
            }
        }
        float mx[4];
#pragma unroll
        for (int r = 0; r < 4; r++) {
            float m = sf[0][r];
#pragma unroll
            for (int kt = 1; kt < 14; kt++) m = fmaxf(m, sf[kt][r]);
            mx[r] = m;
        }
#pragma unroll
        for (int d = 1; d < 16; d <<= 1)
#pragma unroll
            for (int r = 0; r < 4; r++)
                mx[r] = fmaxf(mx[r], __shfl_xor(mx[r], d));
        float sum[4] = {0.f, 0.f, 0.f, 0.f};
#pragma unroll
        for (int kt = 0; kt < 14; kt++)
#pragma unroll
            for (int r = 0; r < 4; r++) {
                float p = __expf(sf[kt][r] - mx[r]);
                sf[kt][r] = p;
                sum[r] += p;
            }
#pragma unroll
        for (int d = 1; d < 16; d <<= 1)
#pragma unroll
            for (int r = 0; r < 4; r++)
                sum[r] += __shfl_xor(sum[r], d);

        f32x4 oacc[2] = {};
#pragma unroll
        for (int kc = 0; kc < 7; kc++) {
#pragma unroll
            for (int r = 0; r < 4; r++) {
                P[(lq * 4 + r) * P_S + lr]      = f2bf(sf[2 * kc][r]);
                P[(lq * 4 + r) * P_S + 16 + lr] = f2bf(sf[2 * kc + 1][r]);
            }
            s16x8 aP = *(const s16x8*)&P[lr * P_S + lq * 8];
#pragma unroll
            for (int dt = 0; dt < 2; dt++) {
                s16x8 bV = *(const s16x8*)&Vt[(dt * 16 + lr) * VT_S + kc * 32 + lq * 8];
                oacc[dt] = __builtin_amdgcn_mfma_f32_16x16x32_bf16(aP, bV, oacc[dt], 0, 0, 0);
            }
        }
#pragma unroll
        for (int r = 0; r < 4; r++) {
            if (qvalid[r]) {
                float inv_l = 1.0f / sum[r];
                size_t ob = base + (size_t)(qt * 16 + lq * 4 + r) * HID;
                o[ob + lr]      = f2bf(oacc[0][r] * inv_l);
                o[ob + 16 + lr] = f2bf(oacc[1][r] * inv_l);
            }
        }
    }
}

// ---------------------------------------------------------------------------
// bf16 MFMA GEMM: C[m,n] = sum_k A[m,k]*B[n,k]. TM x 128 tile, BK=64,
// 256 threads = 4 waves. XOR-swizzled LDS (conflict-free, r6-verified).
// 1D grid, XCD-aware swizzle. Epilogue modes 1/2/3.
// GELU: tanh-form via single v_exp_f32 (~8 VALU ops vs ~30 for erff; max
// deviation from exact ~3e-4 — below bf16 rounding noise, r9).
// ---------------------------------------------------------------------------
__device__ __forceinline__ float gelu_fast(float x) {
    // 0.5x(1+tanh(0.79788456(x+0.044715x^3))) = x - x/(e^{2z}+1)
    float z2 = 1.5957691216f * (x + 0.044715f * x * x * x);  // 2z
    return x - x * __frcp_rn(__expf(z2) + 1.0f);
}

template <int MODE, bool OBF, int TM>
__global__ __launch_bounds__(256) void gemm_mfma(
    const bf16_t* __restrict__ A, const bf16_t* __restrict__ B,
    void* __restrict__ Cv, int M, int N, int K,
    const float* __restrict__ bias, const float* __restrict__ res, float scale)
{
    constexpr int MT = TM / 32;       // m-tiles per wave (4 or 2)
    __shared__ __align__(16) bf16_t As[TM * 64];
    __shared__ __align__(16) bf16_t Bs[128 * 64];

    int tid = threadIdx.x;
    int mb = M / TM, nb = N >> 7;
    int gblk = blockIdx.x;
    int full = mb & ~7;
    int gfull = full * nb;
    int m_, n_;
    if (gblk < gfull) {
        int sg = gblk / (8 * nb), u = gblk - sg * (8 * nb);
        m_ = sg * 8 + (u & 7); n_ = u >> 3;
    } else {
        int u = gblk - gfull, rem = mb - full;
        m_ = full + u % rem; n_ = u / rem;
    }
    int bm = m_ * TM, bn = n_ << 7;

    int w    = tid >> 6;
    int lane = tid & 63;
    int wm = (w & 1) * (TM / 2);
    int wn = (w >> 1) * 64;
    int lr = lane & 15;
    int lq = lane >> 4;

    int srowl = lane >> 3;                    // 0..7
    int scb   = ((lane & 7) ^ srowl) * 16;    // swizzled source byte offset
    const char* Ab = (const char*)A;
    const char* Bb = (const char*)B;

    f32x4 acc[MT][4] = {};

    for (int k0 = 0; k0 < K; k0 += 64) {
#pragma unroll
        for (int j = 0; j < TM / 32; j++) {
            int rb = w * (TM / 4) + j * 8;
            GLOAD_LDS16(Ab + ((size_t)(bm + rb + srowl) * K + k0) * 2 + scb, &As[rb * 64]);
        }
#pragma unroll
        for (int j = 0; j < 4; j++) {
            int rb = w * 32 + j * 8;
            GLOAD_LDS16(Bb + ((size_t)(bn + rb + srowl) * K + k0) * 2 + scb, &Bs[rb * 64]);
        }
        __syncthreads();

        int sw = lr & 7;
#pragma unroll
        for (int kc = 0; kc < 2; kc++) {
            int cof = (((kc << 2) | lq) ^ sw) * 8;
            s16x8 af[MT], bf[4];
#pragma unroll
            for (int t = 0; t < MT; t++)
                af[t] = *(const s16x8*)&As[(wm + t * 16 + lr) * 64 + cof];
#pragma unroll
            for (int t = 0; t < 4; t++)
                bf[t] = *(const s16x8*)&Bs[(wn + t * 16 + lr) * 64 + cof];
#pragma unroll
            for (int tm = 0; tm < MT; tm++)
#pragma unroll
                for (int tn = 0; tn < 4; tn++)
                    acc[tm][tn] = __builtin_amdgcn_mfma_f32_16x16x32_bf16(
                        af[tm], bf[tn], acc[tm][tn], 0, 0, 0);
        }
        __syncthreads();
    }

#pragma unroll
    for (int tm = 0; tm < MT; tm++) {
#pragma unroll
        for (int tn = 0; tn < 4; tn++) {
#pragma unroll
            for (int r = 0; r < 4; r++) {
                int mrow = bm + wm + tm * 16 + lq * 4 + r;
                int ncol = bn + wn + tn * 16 + lr;
                float vacc = acc[tm][tn][r];
                if (MODE == 1) {
                    vacc = (res[(size_t)mrow * N + ncol] + vacc) * scale;
                } else if (MODE == 2) {
                    vacc = gelu_fast(vacc + bias[ncol]);
                } else if (MODE == 3) {
                    vacc = (res[(size_t)mrow * N + ncol] + vacc + bias[ncol]) * scale;
                }
                if (OBF) ((bf16_t*)Cv)[(size_t)mrow * N + ncol] = f2bf(vacc);
                else     ((float*)Cv)[(size_t)mrow * N + ncol] = vacc;
            }
        }
    }
}

// ---------------------------------------------------------------------------
// Launch
// ---------------------------------------------------------------------------
extern "C" void kernel_launch(void* const* d_in, const int* in_sizes, int n_in,
                              void* d_out, int out_size, void* d_ws, size_t ws_size,
                              hipStream_t stream)
{
    const float* x        = (const float*)d_in[0];
    const float* rel_bias = (const float*)d_in[1];
    const float* wq       = (const float*)d_in[2];
    const float* wk       = (const float*)d_in[3];
    const float* wv       = (const float*)d_in[4];
    const float* w_out    = (const float*)d_in[5];
    const float* ln1_g    = (const float*)d_in[6];
    const float* ln1_b    = (const float*)d_in[7];
    const float* ln2_g    = (const float*)d_in[8];
    const float* ln2_b    = (const float*)d_in[9];
    const float* w1       = (const float*)d_in[10];
    const float* b1       = (const float*)d_in[11];
    const float* w2       = (const float*)d_in[12];
    const float* b2       = (const float*)d_in[13];
    float* out = (float*)d_out;
    float* ws  = (float*)d_ws;

    const size_t SZ = (size_t)ROWS * HID;  // 9,633,792 floats
    // Region map (float units):
    //   [0, SZ/2)    o bf16; y2 bf16 [SZ/2, SZ)
    //   [SZ, 1.5SZ)  q bf16 (dies after attn)   } h bf16 [SZ,3SZ) after attn
    //   [2SZ, 2.5SZ) k bf16 (dies after attn)   }
    //   [3SZ, 3.5SZ) v bf16 (dies after attn)
    //   [4SZ, ...)   bf16 weights: wob 768x768, w1b 3072x768, w2b 768x3072
    bf16_t* q_bf = (bf16_t*)(ws + SZ);
    bf16_t* k_bf = (bf16_t*)(ws + 2 * SZ);
    bf16_t* v_bf = (bf16_t*)(ws + 3 * SZ);
    bf16_t* o_bf = (bf16_t*)ws;
    bf16_t* y2b  = (bf16_t*)(ws + SZ / 2);
    bf16_t* h    = (bf16_t*)(ws + SZ);
    bf16_t* wob  = (bf16_t*)(ws + 4 * SZ);
    bf16_t* w1b  = wob + (size_t)HID * HID;
    bf16_t* w2b  = w1b + (size_t)FFN * HID;

    // 0. weight conversions (one launch)
    cvt_w_kernel<<<(WOUT4 + 2 * W14 + 255) / 256, 256, 0, stream>>>(
        w_out, w1, w2, wob, w1b, w2b);

    // 1+2. fused LN1 + q,k,v per-head projections (MFMA, bf16 out)
    ln_qkv_mfma_kernel<<<ROWS / QKV_T, 256, 0, stream>>>(
        x, ln1_g, ln1_b, wq, wk, wv, q_bf, k_bf, v_bf);

    // 3. o = softmax((qk^T + bias)/sqrt(d)) @ v   (MFMA, bf16 out)
    attn_mfma_kernel<<<dim3(NHEAD, NB), 256, 0, stream>>>(q_bf, k_bf, v_bf, rel_bias, o_bf);

    // 4. x1 = (x + o @ w_out^T) * RATE   -> d_out (fp32)   [TM=64: 1176 blks]
    gemm_mfma<1, false, 64><<<(ROWS / 64) * (HID / 128), 256, 0, stream>>>(
        o_bf, wob, out, ROWS, HID, HID, nullptr, x, RATE);

    // 5. y2 = LN2(x1)  (bf16)
    ln_kernel<<<ROWS, 256, 0, stream>>>(out, ln2_g, ln2_b, y2b);

    // 6. h = gelu(y2 @ w1^T + b1)  (bf16)   [TM=128: 2352 blks]
    gemm_mfma<2, true, 128><<<(ROWS / 128) * (FFN / 128), 256, 0, stream>>>(
        y2b, w1b, h, ROWS, FFN, HID, b1, nullptr, 1.0f);

    // 7. out = (x1 + h @ w2^T + b2) * RATE  (fp32)   [TM=64: 1176 blks]
    gemm_mfma<3, false, 64><<<(ROWS / 64) * (HID / 128), 256, 0, stream>>>(
        h, w2b, out, ROWS, HID, FFN, b2, out, RATE);
}